// Round 6
// baseline (191.472 us; speedup 1.0000x reference)
//
#include <hip/hip_runtime.h>

typedef __bf16 bf16;
typedef __bf16 bf16x4 __attribute__((ext_vector_type(4)));
typedef __bf16 bf16x8 __attribute__((ext_vector_type(8)));
typedef float f32x4 __attribute__((ext_vector_type(4)));
typedef float f32x16 __attribute__((ext_vector_type(16)));
typedef unsigned u32x4 __attribute__((ext_vector_type(4)));

static constexpr int Bn = 2, Sn = 2048, Dn = 1024, Hn = 16, HDn = 64;

__device__ __forceinline__ void gload_lds16(const void* g, void* l) {
  __builtin_amdgcn_global_load_lds((__attribute__((address_space(1))) void*)g,
                                   (__attribute__((address_space(3))) void*)l, 16, 0, 0);
}

__device__ __forceinline__ f32x4 mfma_bf16_16x16x32(bf16x8 a, bf16x8 b, f32x4 c) {
  return __builtin_amdgcn_mfma_f32_16x16x32_bf16(a, b, c, 0, 0, 0);
}

__device__ __forceinline__ f32x16 mfma_bf16_32x32x16(bf16x8 a, bf16x8 b, f32x16 c) {
  return __builtin_amdgcn_mfma_f32_32x32x16_bf16(a, b, c, 0, 0, 0);
}

__device__ __forceinline__ float fast_exp2(float x) {
  float r;
  asm("v_exp_f32 %0, %1" : "=v"(r) : "v"(x));
  return r;
}

__device__ __forceinline__ unsigned cvt_pk_bf16(float lo, float hi) {
  unsigned r;
  asm("v_cvt_pk_bf16_f32 %0, %1, %2" : "=v"(r) : "v"(lo), "v"(hi));
  return r;
}

// Cross-half (lane ^ 32) combine via known-good shfl_xor (ds_bpermute path).
__device__ __forceinline__ float cross_half_max(float v) {
  return fmaxf(v, __shfl_xor(v, 32, 64));
}
__device__ __forceinline__ float cross_half_add(float v) {
  return v + __shfl_xor(v, 32, 64);
}
__device__ __forceinline__ unsigned shfl32u(unsigned u) {
  return (unsigned)__shfl_xor((int)u, 32, 64);
}

#define WAITCNT_VM(N) asm volatile("s_waitcnt vmcnt(" #N ")" ::: "memory")
#define WAITCNT_LGKM0 asm volatile("s_waitcnt lgkmcnt(0)" ::: "memory")

// ---------------- fp32 -> bf16 converts (fused launches) ----------------
__global__ __launch_bounds__(256) void cvt_qkv(const float* __restrict__ a0,
                                               const float* __restrict__ a1,
                                               const float* __restrict__ a2,
                                               bf16* __restrict__ o0,
                                               bf16* __restrict__ o1,
                                               bf16* __restrict__ o2, int n4) {
  const float* in = blockIdx.z == 0 ? a0 : (blockIdx.z == 1 ? a1 : a2);
  bf16* out = blockIdx.z == 0 ? o0 : (blockIdx.z == 1 ? o1 : o2);
  int i = blockIdx.x * 256 + threadIdx.x;
  const int stride = gridDim.x * 256;
  for (; i < n4; i += stride) {
    float4 v = reinterpret_cast<const float4*>(in)[i];
    bf16x4 o;
    o[0] = (bf16)v.x; o[1] = (bf16)v.y; o[2] = (bf16)v.z; o[3] = (bf16)v.w;
    reinterpret_cast<bf16x4*>(out)[i] = o;
  }
}

__global__ __launch_bounds__(256) void cvt_w(const float* __restrict__ a0,
                                             const float* __restrict__ a1,
                                             const float* __restrict__ a2,
                                             const float* __restrict__ a3,
                                             bf16* __restrict__ o0,
                                             bf16* __restrict__ o1,
                                             bf16* __restrict__ o2,
                                             bf16* __restrict__ o3,
                                             int n4, float s0) {
  const float* in; bf16* out; float s = 1.0f;
  switch (blockIdx.z) {
    case 0: in = a0; out = o0; s = s0; break;  // Wq gets softmax scale * log2(e)
    case 1: in = a1; out = o1; break;
    case 2: in = a2; out = o2; break;
    default: in = a3; out = o3; break;
  }
  int i = blockIdx.x * 256 + threadIdx.x;
  const int stride = gridDim.x * 256;
  for (; i < n4; i += stride) {
    float4 v = reinterpret_cast<const float4*>(in)[i];
    bf16x4 o;
    o[0] = (bf16)(v.x * s); o[1] = (bf16)(v.y * s);
    o[2] = (bf16)(v.z * s); o[3] = (bf16)(v.w * s);
    reinterpret_cast<bf16x4*>(out)[i] = o;
  }
}

// ---------------- GEMM: C[M,N] = A[M,K] * B[N,K]^T  (m97 structure) ----------------
__device__ __forceinline__ void store_out(float* C, size_t i, float v) { C[i] = v; }
__device__ __forceinline__ void store_out(bf16* C, size_t i, float v) { C[i] = (bf16)v; }

template <typename OutT>
__device__ __forceinline__ void gemm_bt_dev(const bf16* __restrict__ A,
                                            const bf16* __restrict__ Bw,
                                            OutT* __restrict__ C,
                                            int K, int N) {
  const int t = threadIdx.x;
  const int l = t & 63, w = t >> 6;
  const int wr = w >> 1, wc = w & 1;
  const int lc = l & 15, lg = l >> 4;
  const int row0 = blockIdx.y * 128;
  const int col0 = blockIdx.x * 128;

  __shared__ bf16 As[128 * 32];
  __shared__ bf16 Bs[128 * 32];

  f32x4 acc[4][4] = {};

  for (int k0 = 0; k0 < K; k0 += 32) {
#pragma unroll
    for (int i = 0; i < 2; ++i) {
      const int c = i * 256 + t;
      const int r = c >> 2;
      const int scc = (c & 3) ^ (r & 3);
      gload_lds16(A + (size_t)(row0 + r) * K + k0 + scc * 8, As + c * 8);
      gload_lds16(Bw + (size_t)(col0 + r) * K + k0 + scc * 8, Bs + c * 8);
    }
    __syncthreads();

    bf16x8 af[4], bfr[4];
#pragma unroll
    for (int m = 0; m < 4; ++m) {
      const int r = wr * 64 + m * 16 + lc;
      af[m] = *reinterpret_cast<const bf16x8*>(As + r * 32 + ((lg ^ (r & 3)) * 8));
    }
#pragma unroll
    for (int n = 0; n < 4; ++n) {
      const int r = wc * 64 + n * 16 + lc;
      bfr[n] = *reinterpret_cast<const bf16x8*>(Bs + r * 32 + ((lg ^ (r & 3)) * 8));
    }
#pragma unroll
    for (int m = 0; m < 4; ++m)
#pragma unroll
      for (int n = 0; n < 4; ++n)
        acc[m][n] = mfma_bf16_16x16x32(af[m], bfr[n], acc[m][n]);
    __syncthreads();
  }

#pragma unroll
  for (int m = 0; m < 4; ++m) {
    const int rbase = row0 + wr * 64 + m * 16 + lg * 4;
#pragma unroll
    for (int n = 0; n < 4; ++n) {
      const int col = col0 + wc * 64 + n * 16 + lc;
#pragma unroll
      for (int j = 0; j < 4; ++j)
        store_out(C, (size_t)(rbase + j) * N + col, acc[m][n][j]);
    }
  }
}

__global__ __launch_bounds__(256) void gemm_qkv(
    const bf16* __restrict__ qa, const bf16* __restrict__ wq, bf16* __restrict__ qo,
    const bf16* __restrict__ ka, const bf16* __restrict__ wk, bf16* __restrict__ ko,
    const bf16* __restrict__ va, const bf16* __restrict__ wv, bf16* __restrict__ vo) {
  const bf16 *A, *Bw;
  bf16* C;
  if (blockIdx.z == 0)      { A = qa; Bw = wq; C = qo; }
  else if (blockIdx.z == 1) { A = ka; Bw = wk; C = ko; }
  else                      { A = va; Bw = wv; C = vo; }
  gemm_bt_dev<bf16>(A, Bw, C, Dn, Dn);
}

__global__ __launch_bounds__(256) void gemm_out_f32(const bf16* __restrict__ A,
                                                    const bf16* __restrict__ Bw,
                                                    float* __restrict__ C) {
  gemm_bt_dev<float>(A, Bw, C, Dn, Dn);
}

// ---------------- per-batch transpose (S x D) -> (D x S) for V ----------------
__global__ __launch_bounds__(256) void transpose_bsd(const bf16* __restrict__ in,
                                                     bf16* __restrict__ out) {
  __shared__ bf16 tile[64][66];
  const int s0 = blockIdx.x * 64, d0 = blockIdx.y * 64, b = blockIdx.z;
  const int t = threadIdx.x;
#pragma unroll
  for (int i = 0; i < 2; ++i) {
    const int c = i * 256 + t;
    const int r = c >> 3, cc = (c & 7) * 8;
    const bf16x8 v = *reinterpret_cast<const bf16x8*>(
        in + ((size_t)b * Sn + s0 + r) * Dn + d0 + cc);
#pragma unroll
    for (int j = 0; j < 8; ++j) tile[r][cc + j] = v[j];
  }
  __syncthreads();
#pragma unroll
  for (int i = 0; i < 2; ++i) {
    const int c = i * 256 + t;
    const int r = c >> 3, cc = (c & 7) * 8;
    bf16x8 v;
#pragma unroll
    for (int j = 0; j < 8; ++j) v[j] = tile[cc + j][r];
    *reinterpret_cast<bf16x8*>(out + ((size_t)b * Dn + d0 + r) * Sn + s0 + cc) = v;
  }
}

// ---------------- causal flash attention (v4: 1-wave blocks, no barriers) ----------------
// qp pre-scaled by (1/8)*log2(e) via Wq; softmax in exp2 domain.
// qp,kp: (B,S,D); vt: (B,D,S); ctx: (B,S,D)
// One wave per block, 32 Q rows, KVBLK=64, double-buffered LDS, zero barriers:
// each wave prefetches its own next tile and proceeds independently -> waves on a
// SIMD sit at random phases and co-schedule (MFMA/VALU/VMEM overlap).
// S^T = mfma(K, Q): q = lane&31, kv(reg,hi) = (r&3)+8*(r>>2)+4*hi  -> softmax per-lane.
// O^T = mfma(V^T, P): q = lane&31, d per-reg -> alpha/1/l are per-lane scalars.
__global__ __launch_bounds__(64) void flash_attn(const bf16* __restrict__ qp,
                                                 const bf16* __restrict__ kp,
                                                 const bf16* __restrict__ vt,
                                                 bf16* __restrict__ ctx) {
  const int qt = 63 - blockIdx.x;  // reversed: heavy blocks dispatch first
  const int h  = blockIdx.y;
  const int b  = blockIdx.z;
  const int l = threadIdx.x;
  const int lq = l & 31, hi = l >> 5;
  const int qrow0 = qt * 32;  // this wave's 32 Q rows

  __shared__ char smem[32768];  // K dbuf 2x8KB | V dbuf 2x8KB; epilogue aliases K0

  // staging bases: chunk c = i*64 + l -> row r = i*8 + (l>>3), chunk-XOR swizzle
  // scc = (l&7) ^ ((l>>3)&7) is i-invariant (i*8 has no low-3 bits).
  const int rl = l >> 3;
  const int scc = (l & 7) ^ (rl & 7);
  const bf16* kbase = kp + ((size_t)b * Sn + rl) * Dn + h * HDn + scc * 8;
  const bf16* vbase = vt + ((size_t)b * Dn + h * HDn + rl) * Sn + scc * 8;
  const int ldsofs = l * 16;  // bytes

  auto STAGE = [&](int buf, int kv0) {
    char* Kd = smem + buf * 8192 + ldsofs;
    char* Vd = smem + 16384 + buf * 8192 + ldsofs;
    const bf16* ks = kbase + (size_t)kv0 * Dn;
    const bf16* vs = vbase + kv0;
#pragma unroll
    for (int i = 0; i < 8; ++i) {
      gload_lds16(ks + (size_t)i * 8 * Dn, Kd + i * 1024);
      gload_lds16(vs + (size_t)i * 8 * Sn, Vd + i * 1024);
    }
  };

  // Q fragments (B-operand of swapped QK^T): lane holds q=lq, k = kk*16 + hi*8 + e
  bf16x8 qf[4];
#pragma unroll
  for (int kk = 0; kk < 4; ++kk)
    qf[kk] = *reinterpret_cast<const bf16x8*>(
        qp + ((size_t)b * Sn + qrow0 + lq) * Dn + h * HDn + kk * 16 + hi * 8);

  f32x16 oacc0 = {}, oacc1 = {};  // O^T: d 0..31 / 32..63 (per-reg), q = lq
  float mrow = -1e30f, lsum = 0.0f;

  const int nkv = (qt >> 1) + 1;  // exact: no skipped tiles
  int cur = 0;
  STAGE(0, 0);

  for (int kt = 0; kt < nkv; ++kt) {
    if (kt + 1 < nkv) {
      STAGE(cur ^ 1, (kt + 1) * 64);  // 16 loads for next tile in flight
      WAITCNT_VM(16);                 // current tile's 16 loads done
    } else {
      WAITCNT_VM(0);
    }
    __builtin_amdgcn_sched_barrier(0);

    const int kv0 = kt * 64;
    const char* Kc = smem + cur * 8192;
    const char* Vc = smem + 16384 + cur * 8192;

    // S^T = K Q^T : two 32-kv tiles
    f32x16 s0 = {}, s1 = {};
    __builtin_amdgcn_s_setprio(1);
#pragma unroll
    for (int kk = 0; kk < 4; ++kk) {
      const int ch = kk * 2 + hi;
      const int r0 = lq, r1 = 32 + lq;
      const bf16x8 k0 = *reinterpret_cast<const bf16x8*>(Kc + r0 * 128 + ((ch ^ (r0 & 7)) << 4));
      const bf16x8 k1 = *reinterpret_cast<const bf16x8*>(Kc + r1 * 128 + ((ch ^ (r1 & 7)) << 4));
      s0 = mfma_bf16_32x32x16(k0, qf[kk], s0);
      s1 = mfma_bf16_32x32x16(k1, qf[kk], s1);
    }
    __builtin_amdgcn_s_setprio(0);

    // causal mask (diagonal-crossing tiles only)
    if (kv0 + 63 > qrow0) {
      const int qg = qrow0 + lq;
#pragma unroll
      for (int r = 0; r < 16; ++r) {
        const int kvl = (r & 3) + 8 * (r >> 2) + 4 * hi;
        if (kv0 + kvl > qg)      s0[r] = -1e30f;
        if (kv0 + 32 + kvl > qg) s1[r] = -1e30f;
      }
    }

    // in-register online softmax (per-lane row q = lq), defer-max (T13, THR=8)
    float mx[8];
#pragma unroll
    for (int i = 0; i < 8; ++i)
      mx[i] = fmaxf(fmaxf(s0[i], s0[i + 8]), fmaxf(s1[i], s1[i + 8]));
#pragma unroll
    for (int i = 0; i < 4; ++i) mx[i] = fmaxf(mx[i], mx[i + 4]);
    const float tmax_own = fmaxf(fmaxf(mx[0], mx[1]), fmaxf(mx[2], mx[3]));
    const float tmax = cross_half_max(tmax_own);  // pair-uniform over {lq, lq+32}

    float alpha = 1.0f;
    if (!__all(tmax <= mrow + 8.0f)) {  // wave-uniform rescale branch
      const float mn = fmaxf(mrow, tmax);
      alpha = fast_exp2(mrow - mn);
      mrow = mn;
#pragma unroll
      for (int r = 0; r < 16; ++r) { oacc0[r] *= alpha; oacc1[r] *= alpha; }
    }
#pragma unroll
    for (int r = 0; r < 16; ++r) {
      s0[r] = fast_exp2(s0[r] - mrow);  // bounded by 2^8 when deferred
      s1[r] = fast_exp2(s1[r] - mrow);
    }
    float sm[8];
#pragma unroll
    for (int i = 0; i < 8; ++i)
      sm[i] = (s0[i] + s0[i + 8]) + (s1[i] + s1[i + 8]);
#pragma unroll
    for (int i = 0; i < 4; ++i) sm[i] += sm[i + 4];
    float rsum = (sm[0] + sm[1]) + (sm[2] + sm[3]);
    rsum = cross_half_add(rsum);
    lsum = lsum * alpha + rsum;

    // P -> bf16 B-fragments, cross-half redistribution via shfl_xor + select.
    u32x4 pw[4];
#pragma unroll
    for (int c2 = 0; c2 < 4; ++c2) {
      const f32x16& S = (c2 < 2) ? s0 : s1;
      const int base = (c2 & 1) * 8;
      const unsigned u0 = cvt_pk_bf16(S[base + 0], S[base + 1]);
      const unsigned u1 = cvt_pk_bf16(S[base + 2], S[base + 3]);
      const unsigned u2 = cvt_pk_bf16(S[base + 4], S[base + 5]);
      const unsigned u3 = cvt_pk_bf16(S[base + 6], S[base + 7]);
      const unsigned p0 = shfl32u(u0);
      const unsigned p1 = shfl32u(u1);
      const unsigned p2 = shfl32u(u2);
      const unsigned p3 = shfl32u(u3);
      pw[c2][0] = hi ? p2 : u0;
      pw[c2][1] = hi ? p3 : u1;
      pw[c2][2] = hi ? u2 : p0;
      pw[c2][3] = hi ? u3 : p1;
    }

    // O^T += V^T P : A = V^T (d rows), B = P (q cols)
    __builtin_amdgcn_s_setprio(1);
#pragma unroll
    for (int kk = 0; kk < 4; ++kk) {
      const bf16x8 pf = __builtin_bit_cast(bf16x8, pw[kk]);
      const int ch = kk * 2 + hi;
      const int r0 = lq, r1 = 32 + lq;
      const bf16x8 v0 = *reinterpret_cast<const bf16x8*>(Vc + r0 * 128 + ((ch ^ (r0 & 7)) << 4));
      const bf16x8 v1 = *reinterpret_cast<const bf16x8*>(Vc + r1 * 128 + ((ch ^ (r1 & 7)) << 4));
      oacc0 = mfma_bf16_32x32x16(v0, pf, oacc0);
      oacc1 = mfma_bf16_32x32x16(v1, pf, oacc1);
    }
    __builtin_amdgcn_s_setprio(0);

    WAITCNT_LGKM0;  // all LDS reads of buf[cur] retired before it is restaged
    __builtin_amdgcn_sched_barrier(0);
    cur ^= 1;
  }

  // epilogue: O^T/l -> LDS transpose (aliases dead K buffer) -> coalesced stores
  const float inv = 1.0f / lsum;
  bf16* ep = (bf16*)smem;  // [32 q][72 d] bf16 (144B rows, 16B-aligned)
#pragma unroll
  for (int dt = 0; dt < 2; ++dt) {
    const f32x16& O = dt ? oacc1 : oacc0;
#pragma unroll
    for (int g = 0; g < 4; ++g) {
      bf16x4 o4;
#pragma unroll
      for (int j = 0; j < 4; ++j) o4[j] = (bf16)(O[g * 4 + j] * inv);
      const int d = dt * 32 + g * 8 + hi * 4;
      *reinterpret_cast<bf16x4*>(&ep[lq * 72 + d]) = o4;
    }
  }
  WAITCNT_LGKM0;
  __builtin_amdgcn_sched_barrier(0);
#pragma unroll
  for (int i = 0; i < 4; ++i) {
    const int q = i * 8 + (l >> 3);
    const int d0 = (l & 7) * 8;
    const bf16x8 vv = *reinterpret_cast<const bf16x8*>(&ep[q * 72 + d0]);
    *reinterpret_cast<bf16x8*>(
        &ctx[((size_t)b * Sn + qrow0 + q) * Dn + h * HDn + d0]) = vv;
  }
}

// ---------------- launch ----------------
extern "C" void kernel_launch(void* const* d_in, const int* in_sizes, int n_in,
                              void* d_out, int out_size, void* d_ws, size_t ws_size,
                              hipStream_t stream) {
  const float* q  = (const float*)d_in[0];
  const float* k  = (const float*)d_in[1];
  const float* v  = (const float*)d_in[2];
  // d_in[3] = causal mask (structure known; unused)
  const float* Wq = (const float*)d_in[4];
  const float* Wk = (const float*)d_in[5];
  const float* Wv = (const float*)d_in[6];
  const float* Wo = (const float*)d_in[7];

  constexpr size_t BSD = (size_t)Bn * Sn * Dn;
  constexpr size_t DD  = (size_t)Dn * Dn;

  char* p = (char*)d_ws;
  bf16* qbf = (bf16*)p; p += BSD * 2;
  bf16* kbf = (bf16*)p; p += BSD * 2;
  bf16* vbf = (bf16*)p; p += BSD * 2;
  bf16* qpb = (bf16*)p; p += BSD * 2;
  bf16* kpb = (bf16*)p; p += BSD * 2;
  bf16* vpb = (bf16*)p; p += BSD * 2;
  bf16* wqb = (bf16*)p; p += DD * 2;
  bf16* wkb = (bf16*)p; p += DD * 2;
  bf16* wvb = (bf16*)p; p += DD * 2;
  bf16* wob = (bf16*)p; p += DD * 2;
  bf16* vtb  = kbf;   // kbf dead after gemm_qkv
  bf16* ctxb = qbf;   // qbf dead after gemm_qkv

  // fold softmax scale (1/sqrt(64)=1/8) and log2(e) into Wq for exp2-domain softmax
  const float wq_scale = 0.125f * 1.4426950408889634f;

  cvt_qkv<<<dim3(1024, 1, 3), 256, 0, stream>>>(q, k, v, qbf, kbf, vbf, (int)(BSD / 4));
  cvt_w<<<dim3(256, 1, 4), 256, 0, stream>>>(Wq, Wk, Wv, Wo, wqb, wkb, wvb, wob,
                                             (int)(DD / 4), wq_scale);

  gemm_qkv<<<dim3(Dn / 128, (Bn * Sn) / 128, 3), 256, 0, stream>>>(
      qbf, wqb, qpb, kbf, wkb, kpb, vbf, wvb, vpb);

  transpose_bsd<<<dim3(Sn / 64, Dn / 64, Bn), 256, 0, stream>>>(vpb, vtb);

  flash_attn<<<dim3(64, Hn, Bn), 64, 0, stream>>>(qpb, kpb, vtb, ctxb);

  gemm_out_f32<<<dim3(Dn / 128, (Bn * Sn) / 128), 256, 0, stream>>>(ctxb, wob, (float*)d_out);

  (void)in_sizes; (void)n_in; (void)out_size; (void)ws_size;
}

// Round 7
// 159.829 us; speedup vs baseline: 1.1980x; 1.1980x over previous
//
#include <hip/hip_runtime.h>

typedef __bf16 bf16;
typedef __bf16 bf16x4 __attribute__((ext_vector_type(4)));
typedef __bf16 bf16x8 __attribute__((ext_vector_type(8)));
typedef float f32x4 __attribute__((ext_vector_type(4)));
typedef float f32x16 __attribute__((ext_vector_type(16)));
typedef unsigned u32x4 __attribute__((ext_vector_type(4)));

static constexpr int Bn = 2, Sn = 2048, Dn = 1024, Hn = 16, HDn = 64;

__device__ __forceinline__ void gload_lds16(const void* g, void* l) {
  __builtin_amdgcn_global_load_lds((__attribute__((address_space(1))) void*)g,
                                   (__attribute__((address_space(3))) void*)l, 16, 0, 0);
}

__device__ __forceinline__ f32x4 mfma_bf16_16x16x32(bf16x8 a, bf16x8 b, f32x4 c) {
  return __builtin_amdgcn_mfma_f32_16x16x32_bf16(a, b, c, 0, 0, 0);
}

__device__ __forceinline__ f32x16 mfma_bf16_32x32x16(bf16x8 a, bf16x8 b, f32x16 c) {
  return __builtin_amdgcn_mfma_f32_32x32x16_bf16(a, b, c, 0, 0, 0);
}

__device__ __forceinline__ float fast_exp2(float x) {
  float r;
  asm("v_exp_f32 %0, %1" : "=v"(r) : "v"(x));
  return r;
}

__device__ __forceinline__ unsigned cvt_pk_bf16(float lo, float hi) {
  unsigned r;
  asm("v_cvt_pk_bf16_f32 %0, %1, %2" : "=v"(r) : "v"(lo), "v"(hi));
  return r;
}

// Cross-half (lane ^ 32) combine via known-good shfl_xor (ds_bpermute path).
__device__ __forceinline__ float cross_half_max(float v) {
  return fmaxf(v, __shfl_xor(v, 32, 64));
}
__device__ __forceinline__ float cross_half_add(float v) {
  return v + __shfl_xor(v, 32, 64);
}
__device__ __forceinline__ unsigned shfl32u(unsigned u) {
  return (unsigned)__shfl_xor((int)u, 32, 64);
}

#define WAITCNT_VM(N) asm volatile("s_waitcnt vmcnt(" #N ")" ::: "memory")
#define WAITCNT_LGKM0 asm volatile("s_waitcnt lgkmcnt(0)" ::: "memory")

// ---------------- fp32 -> bf16 converts (fused launches) ----------------
__global__ __launch_bounds__(256) void cvt_qkv(const float* __restrict__ a0,
                                               const float* __restrict__ a1,
                                               const float* __restrict__ a2,
                                               bf16* __restrict__ o0,
                                               bf16* __restrict__ o1,
                                               bf16* __restrict__ o2, int n4) {
  const float* in = blockIdx.z == 0 ? a0 : (blockIdx.z == 1 ? a1 : a2);
  bf16* out = blockIdx.z == 0 ? o0 : (blockIdx.z == 1 ? o1 : o2);
  int i = blockIdx.x * 256 + threadIdx.x;
  const int stride = gridDim.x * 256;
  for (; i < n4; i += stride) {
    float4 v = reinterpret_cast<const float4*>(in)[i];
    bf16x4 o;
    o[0] = (bf16)v.x; o[1] = (bf16)v.y; o[2] = (bf16)v.z; o[3] = (bf16)v.w;
    reinterpret_cast<bf16x4*>(out)[i] = o;
  }
}

__global__ __launch_bounds__(256) void cvt_w(const float* __restrict__ a0,
                                             const float* __restrict__ a1,
                                             const float* __restrict__ a2,
                                             const float* __restrict__ a3,
                                             bf16* __restrict__ o0,
                                             bf16* __restrict__ o1,
                                             bf16* __restrict__ o2,
                                             bf16* __restrict__ o3,
                                             int n4, float s0) {
  const float* in; bf16* out; float s = 1.0f;
  switch (blockIdx.z) {
    case 0: in = a0; out = o0; s = s0; break;  // Wq gets softmax scale * log2(e)
    case 1: in = a1; out = o1; break;
    case 2: in = a2; out = o2; break;
    default: in = a3; out = o3; break;
  }
  int i = blockIdx.x * 256 + threadIdx.x;
  const int stride = gridDim.x * 256;
  for (; i < n4; i += stride) {
    float4 v = reinterpret_cast<const float4*>(in)[i];
    bf16x4 o;
    o[0] = (bf16)(v.x * s); o[1] = (bf16)(v.y * s);
    o[2] = (bf16)(v.z * s); o[3] = (bf16)(v.w * s);
    reinterpret_cast<bf16x4*>(out)[i] = o;
  }
}

// ---------------- GEMM: C[M,N] = A[M,K] * B[N,K]^T  (m97 structure) ----------------
__device__ __forceinline__ void store_out(float* C, size_t i, float v) { C[i] = v; }
__device__ __forceinline__ void store_out(bf16* C, size_t i, float v) { C[i] = (bf16)v; }

template <typename OutT>
__device__ __forceinline__ void gemm_bt_dev(const bf16* __restrict__ A,
                                            const bf16* __restrict__ Bw,
                                            OutT* __restrict__ C,
                                            int K, int N) {
  const int t = threadIdx.x;
  const int l = t & 63, w = t >> 6;
  const int wr = w >> 1, wc = w & 1;
  const int lc = l & 15, lg = l >> 4;
  const int row0 = blockIdx.y * 128;
  const int col0 = blockIdx.x * 128;

  __shared__ bf16 As[128 * 32];
  __shared__ bf16 Bs[128 * 32];

  f32x4 acc[4][4] = {};

  for (int k0 = 0; k0 < K; k0 += 32) {
#pragma unroll
    for (int i = 0; i < 2; ++i) {
      const int c = i * 256 + t;
      const int r = c >> 2;
      const int scc = (c & 3) ^ (r & 3);
      gload_lds16(A + (size_t)(row0 + r) * K + k0 + scc * 8, As + c * 8);
      gload_lds16(Bw + (size_t)(col0 + r) * K + k0 + scc * 8, Bs + c * 8);
    }
    __syncthreads();

    bf16x8 af[4], bfr[4];
#pragma unroll
    for (int m = 0; m < 4; ++m) {
      const int r = wr * 64 + m * 16 + lc;
      af[m] = *reinterpret_cast<const bf16x8*>(As + r * 32 + ((lg ^ (r & 3)) * 8));
    }
#pragma unroll
    for (int n = 0; n < 4; ++n) {
      const int r = wc * 64 + n * 16 + lc;
      bfr[n] = *reinterpret_cast<const bf16x8*>(Bs + r * 32 + ((lg ^ (r & 3)) * 8));
    }
#pragma unroll
    for (int m = 0; m < 4; ++m)
#pragma unroll
      for (int n = 0; n < 4; ++n)
        acc[m][n] = mfma_bf16_16x16x32(af[m], bfr[n], acc[m][n]);
    __syncthreads();
  }

#pragma unroll
  for (int m = 0; m < 4; ++m) {
    const int rbase = row0 + wr * 64 + m * 16 + lg * 4;
#pragma unroll
    for (int n = 0; n < 4; ++n) {
      const int col = col0 + wc * 64 + n * 16 + lc;
#pragma unroll
      for (int j = 0; j < 4; ++j)
        store_out(C, (size_t)(rbase + j) * N + col, acc[m][n][j]);
    }
  }
}

__global__ __launch_bounds__(256) void gemm_qkv(
    const bf16* __restrict__ qa, const bf16* __restrict__ wq, bf16* __restrict__ qo,
    const bf16* __restrict__ ka, const bf16* __restrict__ wk, bf16* __restrict__ ko,
    const bf16* __restrict__ va, const bf16* __restrict__ wv, bf16* __restrict__ vo) {
  const bf16 *A, *Bw;
  bf16* C;
  if (blockIdx.z == 0)      { A = qa; Bw = wq; C = qo; }
  else if (blockIdx.z == 1) { A = ka; Bw = wk; C = ko; }
  else                      { A = va; Bw = wv; C = vo; }
  gemm_bt_dev<bf16>(A, Bw, C, Dn, Dn);
}

__global__ __launch_bounds__(256) void gemm_out_f32(const bf16* __restrict__ A,
                                                    const bf16* __restrict__ Bw,
                                                    float* __restrict__ C) {
  gemm_bt_dev<float>(A, Bw, C, Dn, Dn);
}

// ---------------- per-batch transpose (S x D) -> (D x S) for V ----------------
__global__ __launch_bounds__(256) void transpose_bsd(const bf16* __restrict__ in,
                                                     bf16* __restrict__ out) {
  __shared__ bf16 tile[64][66];
  const int s0 = blockIdx.x * 64, d0 = blockIdx.y * 64, b = blockIdx.z;
  const int t = threadIdx.x;
#pragma unroll
  for (int i = 0; i < 2; ++i) {
    const int c = i * 256 + t;
    const int r = c >> 3, cc = (c & 7) * 8;
    const bf16x8 v = *reinterpret_cast<const bf16x8*>(
        in + ((size_t)b * Sn + s0 + r) * Dn + d0 + cc);
#pragma unroll
    for (int j = 0; j < 8; ++j) tile[r][cc + j] = v[j];
  }
  __syncthreads();
#pragma unroll
  for (int i = 0; i < 2; ++i) {
    const int c = i * 256 + t;
    const int r = c >> 3, cc = (c & 7) * 8;
    bf16x8 v;
#pragma unroll
    for (int j = 0; j < 8; ++j) v[j] = tile[cc + j][r];
    *reinterpret_cast<bf16x8*>(out + ((size_t)b * Dn + d0 + r) * Sn + s0 + cc) = v;
  }
}

// ---------------- causal flash attention (v5: 2-wave blocks, 2-tile pipeline) ------------
// qp pre-scaled by (1/8)*log2(e) via Wq; softmax in exp2 domain.
// qp,kp: (B,S,D); vt: (B,D,S); ctx: (B,S,D)
// Block = 2 waves, QBLK=64 (32 Q rows/wave), KVBLK=64. Grid 1024 blocks (qt reversed).
// LDS 40KB: K dbuf (j&1) 2x8KB, V tri-buf (j%3) 3x8KB -> 4 blocks/CU = 8 waves/CU.
// Pipeline (1 barrier/iter): iter t does [STAGE(t+2) | QK(t+1) MFMA || mask+softmax(t)
// VALU] then PV(t). QK(t+1) and softmax(t) use disjoint registers -> MFMA/VALU overlap.
// Race-freedom: all writes (STAGE) issue post-barrier; all reads of the buffers they
// overwrite completed pre-barrier (K[j&1]: QK(j) is 2 iters earlier; V[j%3]: PV(j) is
// 2 iters earlier; epilogue aliases K region only after the final barrier, when no K
// reads remain).
__global__ __launch_bounds__(128) void flash_attn(const bf16* __restrict__ qp,
                                                  const bf16* __restrict__ kp,
                                                  const bf16* __restrict__ vt,
                                                  bf16* __restrict__ ctx) {
  const int qt = 31 - blockIdx.x;  // reversed: heavy blocks dispatch first
  const int h  = blockIdx.y;
  const int b  = blockIdx.z;
  const int t = threadIdx.x, w = t >> 6, l = t & 63;
  const int lq = l & 31, hi = l >> 5;
  const int qrow0 = qt * 64 + w * 32;  // this wave's 32 Q rows

  __shared__ char smem[40960];  // K: 2x8KB @0 | V: 3x8KB @16384; epilogue aliases K

  // staging: 4 K-chunks + 4 V-chunks per thread (128 threads x 16B x 4 = 8KB tile)
  // chunk c = i*128 + t -> row r = i*16 + (t>>3); scc = (t&7)^((t>>3)&7) (i-invariant)
  const int rl = t >> 3;
  const int scc = (t & 7) ^ (rl & 7);
  const bf16* kbase = kp + ((size_t)b * Sn + rl) * Dn + h * HDn + scc * 8;
  const bf16* vbase = vt + ((size_t)b * Dn + h * HDn + rl) * Sn + scc * 8;

  auto STAGE = [&](int j) {  // stage KV tile j
    const int kv0 = j * 64;
    char* Kd = smem + (j & 1) * 8192 + t * 16;
    char* Vd = smem + 16384 + (j % 3) * 8192 + t * 16;
    const bf16* ks = kbase + (size_t)kv0 * Dn;
    const bf16* vs = vbase + kv0;
#pragma unroll
    for (int i = 0; i < 4; ++i) {
      gload_lds16(ks + (size_t)i * 16 * Dn, Kd + i * 2048);
      gload_lds16(vs + (size_t)i * 16 * Sn, Vd + i * 2048);
    }
  };

  // Q fragments (B-operand of swapped QK^T): lane holds q=lq, k = kk*16 + hi*8 + e
  bf16x8 qf[4];
#pragma unroll
  for (int kk = 0; kk < 4; ++kk)
    qf[kk] = *reinterpret_cast<const bf16x8*>(
        qp + ((size_t)b * Sn + qrow0 + lq) * Dn + h * HDn + kk * 16 + hi * 8);

  f32x16 oacc0 = {}, oacc1 = {};  // O^T: d 0..31 / 32..63 (per-reg), q = lq
  float mrow = -1e30f, lsum = 0.0f;

  // QK^T of tile j -> (s0_, s1_); pure MFMA (mask deferred to softmax phase)
  auto QK = [&](int j, f32x16& s0_, f32x16& s1_) {
    const char* Kc = smem + (j & 1) * 8192;
    __builtin_amdgcn_s_setprio(1);
#pragma unroll
    for (int kk = 0; kk < 4; ++kk) {
      const int ch = kk * 2 + hi;
      const int r0 = lq, r1 = 32 + lq;
      const bf16x8 k0 = *reinterpret_cast<const bf16x8*>(Kc + r0 * 128 + ((ch ^ (r0 & 7)) << 4));
      const bf16x8 k1 = *reinterpret_cast<const bf16x8*>(Kc + r1 * 128 + ((ch ^ (r1 & 7)) << 4));
      s0_ = mfma_bf16_32x32x16(k0, qf[kk], s0_);
      s1_ = mfma_bf16_32x32x16(k1, qf[kk], s1_);
    }
    __builtin_amdgcn_s_setprio(0);
  };

  // mask + online softmax + PV of tile j (consumes s0_, s1_)
  auto SMPV = [&](int j, f32x16& s0, f32x16& s1) {
    const int kv0 = j * 64;
    const char* Vc = smem + 16384 + (j % 3) * 8192;

    if (kv0 + 63 > qrow0) {  // causal mask (diagonal-crossing tiles only)
      const int qg = qrow0 + lq;
#pragma unroll
      for (int r = 0; r < 16; ++r) {
        const int kvl = (r & 3) + 8 * (r >> 2) + 4 * hi;
        if (kv0 + kvl > qg)      s0[r] = -1e30f;
        if (kv0 + 32 + kvl > qg) s1[r] = -1e30f;
      }
    }

    float mx[8];
#pragma unroll
    for (int i = 0; i < 8; ++i)
      mx[i] = fmaxf(fmaxf(s0[i], s0[i + 8]), fmaxf(s1[i], s1[i + 8]));
#pragma unroll
    for (int i = 0; i < 4; ++i) mx[i] = fmaxf(mx[i], mx[i + 4]);
    const float tmax_own = fmaxf(fmaxf(mx[0], mx[1]), fmaxf(mx[2], mx[3]));
    const float tmax = cross_half_max(tmax_own);  // pair-uniform over {lq, lq+32}

    float alpha = 1.0f;
    if (!__all(tmax <= mrow + 8.0f)) {  // defer-max (T13): wave-uniform rescale
      const float mn = fmaxf(mrow, tmax);
      alpha = fast_exp2(mrow - mn);
      mrow = mn;
#pragma unroll
      for (int r = 0; r < 16; ++r) { oacc0[r] *= alpha; oacc1[r] *= alpha; }
    }
#pragma unroll
    for (int r = 0; r < 16; ++r) {
      s0[r] = fast_exp2(s0[r] - mrow);  // bounded by 2^8 when deferred
      s1[r] = fast_exp2(s1[r] - mrow);
    }
    float sm[8];
#pragma unroll
    for (int i = 0; i < 8; ++i)
      sm[i] = (s0[i] + s0[i + 8]) + (s1[i] + s1[i + 8]);
#pragma unroll
    for (int i = 0; i < 4; ++i) sm[i] += sm[i + 4];
    float rsum = (sm[0] + sm[1]) + (sm[2] + sm[3]);
    rsum = cross_half_add(rsum);
    lsum = lsum * alpha + rsum;

    // P -> bf16 B-fragments, cross-half redistribution via shfl_xor + select
    u32x4 pw[4];
#pragma unroll
    for (int c2 = 0; c2 < 4; ++c2) {
      const f32x16& S = (c2 < 2) ? s0 : s1;
      const int base = (c2 & 1) * 8;
      const unsigned u0 = cvt_pk_bf16(S[base + 0], S[base + 1]);
      const unsigned u1 = cvt_pk_bf16(S[base + 2], S[base + 3]);
      const unsigned u2 = cvt_pk_bf16(S[base + 4], S[base + 5]);
      const unsigned u3 = cvt_pk_bf16(S[base + 6], S[base + 7]);
      const unsigned p0 = shfl32u(u0);
      const unsigned p1 = shfl32u(u1);
      const unsigned p2 = shfl32u(u2);
      const unsigned p3 = shfl32u(u3);
      pw[c2][0] = hi ? p2 : u0;
      pw[c2][1] = hi ? p3 : u1;
      pw[c2][2] = hi ? u2 : p0;
      pw[c2][3] = hi ? u3 : p1;
    }

    __builtin_amdgcn_s_setprio(1);
#pragma unroll
    for (int kk = 0; kk < 4; ++kk) {
      const bf16x8 pf = __builtin_bit_cast(bf16x8, pw[kk]);
      const int ch = kk * 2 + hi;
      const int r0 = lq, r1 = 32 + lq;
      const bf16x8 v0 = *reinterpret_cast<const bf16x8*>(Vc + r0 * 128 + ((ch ^ (r0 & 7)) << 4));
      const bf16x8 v1 = *reinterpret_cast<const bf16x8*>(Vc + r1 * 128 + ((ch ^ (r1 & 7)) << 4));
      oacc0 = mfma_bf16_32x32x16(v0, pf, oacc0);
      oacc1 = mfma_bf16_32x32x16(v1, pf, oacc1);
    }
    __builtin_amdgcn_s_setprio(0);
  };

  const int nkv = qt + 1;
  STAGE(0);
  if (nkv > 1) { STAGE(1); WAITCNT_VM(8); } else { WAITCNT_VM(0); }
  __builtin_amdgcn_sched_barrier(0);
  __builtin_amdgcn_s_barrier();
  __builtin_amdgcn_sched_barrier(0);

  f32x16 sp0 = {}, sp1 = {};
  QK(0, sp0, sp1);

  for (int kt = 0; kt < nkv; ++kt) {
    WAITCNT_VM(0);  // waits the (kt+1)-tile loads; no-op on the final iteration
    __builtin_amdgcn_sched_barrier(0);
    __builtin_amdgcn_s_barrier();
    __builtin_amdgcn_sched_barrier(0);

    if (kt + 2 < nkv) STAGE(kt + 2);
    f32x16 sn0 = {}, sn1 = {};
    if (kt + 1 < nkv) QK(kt + 1, sn0, sn1);  // MFMA, overlaps softmax(kt) below
    SMPV(kt, sp0, sp1);                      // VALU-heavy + PV MFMA
    sp0 = sn0; sp1 = sn1;
  }

  // epilogue: O^T/l -> per-wave LDS transpose (aliases K region) -> coalesced stores
  const float inv = 1.0f / lsum;
  bf16* ep = (bf16*)(smem + w * 4608);  // [32 q][72 d] bf16 per wave
#pragma unroll
  for (int dt = 0; dt < 2; ++dt) {
    const f32x16& O = dt ? oacc1 : oacc0;
#pragma unroll
    for (int g = 0; g < 4; ++g) {
      bf16x4 o4;
#pragma unroll
      for (int j = 0; j < 4; ++j) o4[j] = (bf16)(O[g * 4 + j] * inv);
      const int d = dt * 32 + g * 8 + hi * 4;
      *reinterpret_cast<bf16x4*>(&ep[lq * 72 + d]) = o4;
    }
  }
  WAITCNT_LGKM0;
  __builtin_amdgcn_sched_barrier(0);
#pragma unroll
  for (int i = 0; i < 4; ++i) {
    const int q = i * 8 + (l >> 3);
    const int d0 = (l & 7) * 8;
    const bf16x8 vv = *reinterpret_cast<const bf16x8*>(&ep[q * 72 + d0]);
    *reinterpret_cast<bf16x8*>(
        &ctx[((size_t)b * Sn + qrow0 + q) * Dn + h * HDn + d0]) = vv;
  }
}

// ---------------- launch ----------------
extern "C" void kernel_launch(void* const* d_in, const int* in_sizes, int n_in,
                              void* d_out, int out_size, void* d_ws, size_t ws_size,
                              hipStream_t stream) {
  const float* q  = (const float*)d_in[0];
  const float* k  = (const float*)d_in[1];
  const float* v  = (const float*)d_in[2];
  // d_in[3] = causal mask (structure known; unused)
  const float* Wq = (const float*)d_in[4];
  const float* Wk = (const float*)d_in[5];
  const float* Wv = (const float*)d_in[6];
  const float* Wo = (const float*)d_in[7];

  constexpr size_t BSD = (size_t)Bn * Sn * Dn;
  constexpr size_t DD  = (size_t)Dn * Dn;

  char* p = (char*)d_ws;
  bf16* qbf = (bf16*)p; p += BSD * 2;
  bf16* kbf = (bf16*)p; p += BSD * 2;
  bf16* vbf = (bf16*)p; p += BSD * 2;
  bf16* qpb = (bf16*)p; p += BSD * 2;
  bf16* kpb = (bf16*)p; p += BSD * 2;
  bf16* vpb = (bf16*)p; p += BSD * 2;
  bf16* wqb = (bf16*)p; p += DD * 2;
  bf16* wkb = (bf16*)p; p += DD * 2;
  bf16* wvb = (bf16*)p; p += DD * 2;
  bf16* wob = (bf16*)p; p += DD * 2;
  bf16* vtb  = kbf;   // kbf dead after gemm_qkv
  bf16* ctxb = qbf;   // qbf dead after gemm_qkv

  // fold softmax scale (1/sqrt(64)=1/8) and log2(e) into Wq for exp2-domain softmax
  const float wq_scale = 0.125f * 1.4426950408889634f;

  cvt_qkv<<<dim3(1024, 1, 3), 256, 0, stream>>>(q, k, v, qbf, kbf, vbf, (int)(BSD / 4));
  cvt_w<<<dim3(256, 1, 4), 256, 0, stream>>>(Wq, Wk, Wv, Wo, wqb, wkb, wvb, wob,
                                             (int)(DD / 4), wq_scale);

  gemm_qkv<<<dim3(Dn / 128, (Bn * Sn) / 128, 3), 256, 0, stream>>>(
      qbf, wqb, qpb, kbf, wkb, kpb, vbf, wvb, vpb);

  transpose_bsd<<<dim3(Sn / 64, Dn / 64, Bn), 256, 0, stream>>>(vpb, vtb);

  flash_attn<<<dim3(32, Hn, Bn), 128, 0, stream>>>(qpb, kpb, vtb, ctxb);

  gemm_out_f32<<<dim3(Dn / 128, (Bn * Sn) / 128), 256, 0, stream>>>(ctxb, wob, (float*)d_out);

  (void)in_sizes; (void)n_in; (void)out_size; (void)ws_size;
}

// Round 8
// 159.303 us; speedup vs baseline: 1.2019x; 1.0033x over previous
//
#include <hip/hip_runtime.h>

typedef __bf16 bf16;
typedef __bf16 bf16x4 __attribute__((ext_vector_type(4)));
typedef __bf16 bf16x8 __attribute__((ext_vector_type(8)));
typedef float f32x4 __attribute__((ext_vector_type(4)));
typedef float f32x16 __attribute__((ext_vector_type(16)));
typedef unsigned u32x4 __attribute__((ext_vector_type(4)));

static constexpr int Bn = 2, Sn = 2048, Dn = 1024, Hn = 16, HDn = 64;

__device__ __forceinline__ void gload_lds16(const void* g, void* l) {
  __builtin_amdgcn_global_load_lds((__attribute__((address_space(1))) void*)g,
                                   (__attribute__((address_space(3))) void*)l, 16, 0, 0);
}

__device__ __forceinline__ f32x4 mfma_bf16_16x16x32(bf16x8 a, bf16x8 b, f32x4 c) {
  return __builtin_amdgcn_mfma_f32_16x16x32_bf16(a, b, c, 0, 0, 0);
}

__device__ __forceinline__ f32x16 mfma_bf16_32x32x16(bf16x8 a, bf16x8 b, f32x16 c) {
  return __builtin_amdgcn_mfma_f32_32x32x16_bf16(a, b, c, 0, 0, 0);
}

__device__ __forceinline__ float fast_exp2(float x) {
  float r;
  asm("v_exp_f32 %0, %1" : "=v"(r) : "v"(x));
  return r;
}

__device__ __forceinline__ unsigned cvt_pk_bf16(float lo, float hi) {
  unsigned r;
  asm("v_cvt_pk_bf16_f32 %0, %1, %2" : "=v"(r) : "v"(lo), "v"(hi));
  return r;
}

// Cross-half (lane ^ 32) combine via known-good shfl_xor (ds_bpermute path).
__device__ __forceinline__ float cross_half_max(float v) {
  return fmaxf(v, __shfl_xor(v, 32, 64));
}
__device__ __forceinline__ float cross_half_add(float v) {
  return v + __shfl_xor(v, 32, 64);
}
__device__ __forceinline__ unsigned shfl32u(unsigned u) {
  return (unsigned)__shfl_xor((int)u, 32, 64);
}

#define WAITCNT_VM(N) asm volatile("s_waitcnt vmcnt(" #N ")" ::: "memory")
#define WAITCNT_LGKM0 asm volatile("s_waitcnt lgkmcnt(0)" ::: "memory")

// ---------------- fp32 -> bf16 converts (fused launches) ----------------
__global__ __launch_bounds__(256) void cvt_qkv(const float* __restrict__ a0,
                                               const float* __restrict__ a1,
                                               const float* __restrict__ a2,
                                               bf16* __restrict__ o0,
                                               bf16* __restrict__ o1,
                                               bf16* __restrict__ o2, int n4) {
  const float* in = blockIdx.z == 0 ? a0 : (blockIdx.z == 1 ? a1 : a2);
  bf16* out = blockIdx.z == 0 ? o0 : (blockIdx.z == 1 ? o1 : o2);
  int i = blockIdx.x * 256 + threadIdx.x;
  const int stride = gridDim.x * 256;
  for (; i < n4; i += stride) {
    float4 v = reinterpret_cast<const float4*>(in)[i];
    bf16x4 o;
    o[0] = (bf16)v.x; o[1] = (bf16)v.y; o[2] = (bf16)v.z; o[3] = (bf16)v.w;
    reinterpret_cast<bf16x4*>(out)[i] = o;
  }
}

__global__ __launch_bounds__(256) void cvt_w(const float* __restrict__ a0,
                                             const float* __restrict__ a1,
                                             const float* __restrict__ a2,
                                             const float* __restrict__ a3,
                                             bf16* __restrict__ o0,
                                             bf16* __restrict__ o1,
                                             bf16* __restrict__ o2,
                                             bf16* __restrict__ o3,
                                             int n4, float s0) {
  const float* in; bf16* out; float s = 1.0f;
  switch (blockIdx.z) {
    case 0: in = a0; out = o0; s = s0; break;  // Wq gets softmax scale * log2(e)
    case 1: in = a1; out = o1; break;
    case 2: in = a2; out = o2; break;
    default: in = a3; out = o3; break;
  }
  int i = blockIdx.x * 256 + threadIdx.x;
  const int stride = gridDim.x * 256;
  for (; i < n4; i += stride) {
    float4 v = reinterpret_cast<const float4*>(in)[i];
    bf16x4 o;
    o[0] = (bf16)(v.x * s); o[1] = (bf16)(v.y * s);
    o[2] = (bf16)(v.z * s); o[3] = (bf16)(v.w * s);
    reinterpret_cast<bf16x4*>(out)[i] = o;
  }
}

// ---------------- GEMM: C[M,N] = A[M,K] * B[N,K]^T  (m97 structure) ----------------
__device__ __forceinline__ void store_out(float* C, size_t i, float v) { C[i] = v; }
__device__ __forceinline__ void store_out(bf16* C, size_t i, float v) { C[i] = (bf16)v; }

template <typename OutT>
__device__ __forceinline__ void gemm_bt_dev(const bf16* __restrict__ A,
                                            const bf16* __restrict__ Bw,
                                            OutT* __restrict__ C,
                                            int K, int N) {
  const int t = threadIdx.x;
  const int l = t & 63, w = t >> 6;
  const int wr = w >> 1, wc = w & 1;
  const int lc = l & 15, lg = l >> 4;
  const int row0 = blockIdx.y * 128;
  const int col0 = blockIdx.x * 128;

  __shared__ bf16 As[128 * 32];
  __shared__ bf16 Bs[128 * 32];

  f32x4 acc[4][4] = {};

  for (int k0 = 0; k0 < K; k0 += 32) {
#pragma unroll
    for (int i = 0; i < 2; ++i) {
      const int c = i * 256 + t;
      const int r = c >> 2;
      const int scc = (c & 3) ^ (r & 3);
      gload_lds16(A + (size_t)(row0 + r) * K + k0 + scc * 8, As + c * 8);
      gload_lds16(Bw + (size_t)(col0 + r) * K + k0 + scc * 8, Bs + c * 8);
    }
    __syncthreads();

    bf16x8 af[4], bfr[4];
#pragma unroll
    for (int m = 0; m < 4; ++m) {
      const int r = wr * 64 + m * 16 + lc;
      af[m] = *reinterpret_cast<const bf16x8*>(As + r * 32 + ((lg ^ (r & 3)) * 8));
    }
#pragma unroll
    for (int n = 0; n < 4; ++n) {
      const int r = wc * 64 + n * 16 + lc;
      bfr[n] = *reinterpret_cast<const bf16x8*>(Bs + r * 32 + ((lg ^ (r & 3)) * 8));
    }
#pragma unroll
    for (int m = 0; m < 4; ++m)
#pragma unroll
      for (int n = 0; n < 4; ++n)
        acc[m][n] = mfma_bf16_16x16x32(af[m], bfr[n], acc[m][n]);
    __syncthreads();
  }

#pragma unroll
  for (int m = 0; m < 4; ++m) {
    const int rbase = row0 + wr * 64 + m * 16 + lg * 4;
#pragma unroll
    for (int n = 0; n < 4; ++n) {
      const int col = col0 + wc * 64 + n * 16 + lc;
#pragma unroll
      for (int j = 0; j < 4; ++j)
        store_out(C, (size_t)(rbase + j) * N + col, acc[m][n][j]);
    }
  }
}

__global__ __launch_bounds__(256) void gemm_qkv(
    const bf16* __restrict__ qa, const bf16* __restrict__ wq, bf16* __restrict__ qo,
    const bf16* __restrict__ ka, const bf16* __restrict__ wk, bf16* __restrict__ ko,
    const bf16* __restrict__ va, const bf16* __restrict__ wv, bf16* __restrict__ vo) {
  const bf16 *A, *Bw;
  bf16* C;
  if (blockIdx.z == 0)      { A = qa; Bw = wq; C = qo; }
  else if (blockIdx.z == 1) { A = ka; Bw = wk; C = ko; }
  else                      { A = va; Bw = wv; C = vo; }
  gemm_bt_dev<bf16>(A, Bw, C, Dn, Dn);
}

__global__ __launch_bounds__(256) void gemm_out_f32(const bf16* __restrict__ A,
                                                    const bf16* __restrict__ Bw,
                                                    float* __restrict__ C) {
  gemm_bt_dev<float>(A, Bw, C, Dn, Dn);
}

// ---------------- per-batch transpose (S x D) -> (D x S) for V ----------------
__global__ __launch_bounds__(256) void transpose_bsd(const bf16* __restrict__ in,
                                                     bf16* __restrict__ out) {
  __shared__ bf16 tile[64][66];
  const int s0 = blockIdx.x * 64, d0 = blockIdx.y * 64, b = blockIdx.z;
  const int t = threadIdx.x;
#pragma unroll
  for (int i = 0; i < 2; ++i) {
    const int c = i * 256 + t;
    const int r = c >> 3, cc = (c & 7) * 8;
    const bf16x8 v = *reinterpret_cast<const bf16x8*>(
        in + ((size_t)b * Sn + s0 + r) * Dn + d0 + cc);
#pragma unroll
    for (int j = 0; j < 8; ++j) tile[r][cc + j] = v[j];
  }
  __syncthreads();
#pragma unroll
  for (int i = 0; i < 2; ++i) {
    const int c = i * 256 + t;
    const int r = c >> 3, cc = (c & 7) * 8;
    bf16x8 v;
#pragma unroll
    for (int j = 0; j < 8; ++j) v[j] = tile[cc + j][r];
    *reinterpret_cast<bf16x8*>(out + ((size_t)b * Dn + d0 + r) * Sn + s0 + cc) = v;
  }
}

// ---------------- causal flash attention (v6: R7 pipeline + XCD-locality swizzle) --------
// qp pre-scaled by (1/8)*log2(e) via Wq; softmax in exp2 domain.
// qp,kp: (B,S,D); vt: (B,D,S); ctx: (B,S,D)
// Block = 2 waves, QBLK=64 (32 Q rows/wave), KVBLK=64. Grid = 1024 1-D blocks.
// XCD swizzle (T1): dispatch assigns XCD = n%8. We map so each (h,b) group's 32
// qt-blocks (which share the same 512KB K/V stream) land on ONE XCD:
//   g = (n&7) + 8*(n>>8)   (group id = h + 16*b, 32 groups)
//   m = (n>>3) & 31        (member -> qt = 31-m, heavy-first)
// Each XCD hosts exactly 4 complete groups -> 2MB K/V working set < 4MB L2/XCD.
// Bijective for 1024 = 8 XCDs x 4 groups x 32 members.
// LDS 40KB: K dbuf (j&1) 2x8KB, V tri-buf (j%3) 3x8KB -> 4 blocks/CU.
__global__ __launch_bounds__(128) void flash_attn(const bf16* __restrict__ qp,
                                                  const bf16* __restrict__ kp,
                                                  const bf16* __restrict__ vt,
                                                  bf16* __restrict__ ctx) {
  const int n = blockIdx.x;
  const int g = (n & 7) + 8 * (n >> 8);
  const int m = (n >> 3) & 31;
  const int qt = 31 - m;   // heavy blocks first within each group
  const int h  = g & 15;
  const int b  = g >> 4;
  const int t = threadIdx.x, w = t >> 6, l = t & 63;
  const int lq = l & 31, hi = l >> 5;
  const int qrow0 = qt * 64 + w * 32;  // this wave's 32 Q rows

  __shared__ char smem[40960];  // K: 2x8KB @0 | V: 3x8KB @16384; epilogue aliases K

  // staging: 4 K-chunks + 4 V-chunks per thread (128 threads x 16B x 4 = 8KB tile)
  const int rl = t >> 3;
  const int scc = (t & 7) ^ (rl & 7);
  const bf16* kbase = kp + ((size_t)b * Sn + rl) * Dn + h * HDn + scc * 8;
  const bf16* vbase = vt + ((size_t)b * Dn + h * HDn + rl) * Sn + scc * 8;

  auto STAGE = [&](int j) {  // stage KV tile j
    const int kv0 = j * 64;
    char* Kd = smem + (j & 1) * 8192 + t * 16;
    char* Vd = smem + 16384 + (j % 3) * 8192 + t * 16;
    const bf16* ks = kbase + (size_t)kv0 * Dn;
    const bf16* vs = vbase + kv0;
#pragma unroll
    for (int i = 0; i < 4; ++i) {
      gload_lds16(ks + (size_t)i * 16 * Dn, Kd + i * 2048);
      gload_lds16(vs + (size_t)i * 16 * Sn, Vd + i * 2048);
    }
  };

  // Q fragments (B-operand of swapped QK^T): lane holds q=lq, k = kk*16 + hi*8 + e
  bf16x8 qf[4];
#pragma unroll
  for (int kk = 0; kk < 4; ++kk)
    qf[kk] = *reinterpret_cast<const bf16x8*>(
        qp + ((size_t)b * Sn + qrow0 + lq) * Dn + h * HDn + kk * 16 + hi * 8);

  f32x16 oacc0 = {}, oacc1 = {};  // O^T: d 0..31 / 32..63 (per-reg), q = lq
  float mrow = -1e30f, lsum = 0.0f;

  // QK^T of tile j -> (s0_, s1_); pure MFMA (mask deferred to softmax phase)
  auto QK = [&](int j, f32x16& s0_, f32x16& s1_) {
    const char* Kc = smem + (j & 1) * 8192;
    __builtin_amdgcn_s_setprio(1);
#pragma unroll
    for (int kk = 0; kk < 4; ++kk) {
      const int ch = kk * 2 + hi;
      const int r0 = lq, r1 = 32 + lq;
      const bf16x8 k0 = *reinterpret_cast<const bf16x8*>(Kc + r0 * 128 + ((ch ^ (r0 & 7)) << 4));
      const bf16x8 k1 = *reinterpret_cast<const bf16x8*>(Kc + r1 * 128 + ((ch ^ (r1 & 7)) << 4));
      s0_ = mfma_bf16_32x32x16(k0, qf[kk], s0_);
      s1_ = mfma_bf16_32x32x16(k1, qf[kk], s1_);
    }
    __builtin_amdgcn_s_setprio(0);
  };

  // mask + online softmax + PV of tile j (consumes s0_, s1_)
  auto SMPV = [&](int j, f32x16& s0, f32x16& s1) {
    const int kv0 = j * 64;
    const char* Vc = smem + 16384 + (j % 3) * 8192;

    if (kv0 + 63 > qrow0) {  // causal mask (diagonal-crossing tiles only)
      const int qg = qrow0 + lq;
#pragma unroll
      for (int r = 0; r < 16; ++r) {
        const int kvl = (r & 3) + 8 * (r >> 2) + 4 * hi;
        if (kv0 + kvl > qg)      s0[r] = -1e30f;
        if (kv0 + 32 + kvl > qg) s1[r] = -1e30f;
      }
    }

    float mx[8];
#pragma unroll
    for (int i = 0; i < 8; ++i)
      mx[i] = fmaxf(fmaxf(s0[i], s0[i + 8]), fmaxf(s1[i], s1[i + 8]));
#pragma unroll
    for (int i = 0; i < 4; ++i) mx[i] = fmaxf(mx[i], mx[i + 4]);
    const float tmax_own = fmaxf(fmaxf(mx[0], mx[1]), fmaxf(mx[2], mx[3]));
    const float tmax = cross_half_max(tmax_own);  // pair-uniform over {lq, lq+32}

    float alpha = 1.0f;
    if (!__all(tmax <= mrow + 8.0f)) {  // defer-max (T13): wave-uniform rescale
      const float mn = fmaxf(mrow, tmax);
      alpha = fast_exp2(mrow - mn);
      mrow = mn;
#pragma unroll
      for (int r = 0; r < 16; ++r) { oacc0[r] *= alpha; oacc1[r] *= alpha; }
    }
#pragma unroll
    for (int r = 0; r < 16; ++r) {
      s0[r] = fast_exp2(s0[r] - mrow);  // bounded by 2^8 when deferred
      s1[r] = fast_exp2(s1[r] - mrow);
    }
    float sm[8];
#pragma unroll
    for (int i = 0; i < 8; ++i)
      sm[i] = (s0[i] + s0[i + 8]) + (s1[i] + s1[i + 8]);
#pragma unroll
    for (int i = 0; i < 4; ++i) sm[i] += sm[i + 4];
    float rsum = (sm[0] + sm[1]) + (sm[2] + sm[3]);
    rsum = cross_half_add(rsum);
    lsum = lsum * alpha + rsum;

    // P -> bf16 B-fragments, cross-half redistribution via shfl_xor + select
    u32x4 pw[4];
#pragma unroll
    for (int c2 = 0; c2 < 4; ++c2) {
      const f32x16& S = (c2 < 2) ? s0 : s1;
      const int base = (c2 & 1) * 8;
      const unsigned u0 = cvt_pk_bf16(S[base + 0], S[base + 1]);
      const unsigned u1 = cvt_pk_bf16(S[base + 2], S[base + 3]);
      const unsigned u2 = cvt_pk_bf16(S[base + 4], S[base + 5]);
      const unsigned u3 = cvt_pk_bf16(S[base + 6], S[base + 7]);
      const unsigned p0 = shfl32u(u0);
      const unsigned p1 = shfl32u(u1);
      const unsigned p2 = shfl32u(u2);
      const unsigned p3 = shfl32u(u3);
      pw[c2][0] = hi ? p2 : u0;
      pw[c2][1] = hi ? p3 : u1;
      pw[c2][2] = hi ? u2 : p0;
      pw[c2][3] = hi ? u3 : p1;
    }

    __builtin_amdgcn_s_setprio(1);
#pragma unroll
    for (int kk = 0; kk < 4; ++kk) {
      const bf16x8 pf = __builtin_bit_cast(bf16x8, pw[kk]);
      const int ch = kk * 2 + hi;
      const int r0 = lq, r1 = 32 + lq;
      const bf16x8 v0 = *reinterpret_cast<const bf16x8*>(Vc + r0 * 128 + ((ch ^ (r0 & 7)) << 4));
      const bf16x8 v1 = *reinterpret_cast<const bf16x8*>(Vc + r1 * 128 + ((ch ^ (r1 & 7)) << 4));
      oacc0 = mfma_bf16_32x32x16(v0, pf, oacc0);
      oacc1 = mfma_bf16_32x32x16(v1, pf, oacc1);
    }
    __builtin_amdgcn_s_setprio(0);
  };

  const int nkv = qt + 1;
  STAGE(0);
  if (nkv > 1) { STAGE(1); WAITCNT_VM(8); } else { WAITCNT_VM(0); }
  __builtin_amdgcn_sched_barrier(0);
  __builtin_amdgcn_s_barrier();
  __builtin_amdgcn_sched_barrier(0);

  f32x16 sp0 = {}, sp1 = {};
  QK(0, sp0, sp1);

  for (int kt = 0; kt < nkv; ++kt) {
    WAITCNT_VM(0);  // waits the (kt+1)-tile loads; no-op on the final iteration
    __builtin_amdgcn_sched_barrier(0);
    __builtin_amdgcn_s_barrier();
    __builtin_amdgcn_sched_barrier(0);

    if (kt + 2 < nkv) STAGE(kt + 2);
    f32x16 sn0 = {}, sn1 = {};
    if (kt + 1 < nkv) QK(kt + 1, sn0, sn1);  // MFMA, overlaps softmax(kt) below
    SMPV(kt, sp0, sp1);                      // VALU-heavy + PV MFMA
    sp0 = sn0; sp1 = sn1;
  }

  // epilogue: O^T/l -> per-wave LDS transpose (aliases K region) -> coalesced stores
  const float inv = 1.0f / lsum;
  bf16* ep = (bf16*)(smem + w * 4608);  // [32 q][72 d] bf16 per wave
#pragma unroll
  for (int dt = 0; dt < 2; ++dt) {
    const f32x16& O = dt ? oacc1 : oacc0;
#pragma unroll
    for (int g2 = 0; g2 < 4; ++g2) {
      bf16x4 o4;
#pragma unroll
      for (int j = 0; j < 4; ++j) o4[j] = (bf16)(O[g2 * 4 + j] * inv);
      const int d = dt * 32 + g2 * 8 + hi * 4;
      *reinterpret_cast<bf16x4*>(&ep[lq * 72 + d]) = o4;
    }
  }
  WAITCNT_LGKM0;
  __builtin_amdgcn_sched_barrier(0);
#pragma unroll
  for (int i = 0; i < 4; ++i) {
    const int q = i * 8 + (l >> 3);
    const int d0 = (l & 7) * 8;
    const bf16x8 vv = *reinterpret_cast<const bf16x8*>(&ep[q * 72 + d0]);
    *reinterpret_cast<bf16x8*>(
        &ctx[((size_t)b * Sn + qrow0 + q) * Dn + h * HDn + d0]) = vv;
  }
}

// ---------------- launch ----------------
extern "C" void kernel_launch(void* const* d_in, const int* in_sizes, int n_in,
                              void* d_out, int out_size, void* d_ws, size_t ws_size,
                              hipStream_t stream) {
  const float* q  = (const float*)d_in[0];
  const float* k  = (const float*)d_in[1];
  const float* v  = (const float*)d_in[2];
  // d_in[3] = causal mask (structure known; unused)
  const float* Wq = (const float*)d_in[4];
  const float* Wk = (const float*)d_in[5];
  const float* Wv = (const float*)d_in[6];
  const float* Wo = (const float*)d_in[7];

  constexpr size_t BSD = (size_t)Bn * Sn * Dn;
  constexpr size_t DD  = (size_t)Dn * Dn;

  char* p = (char*)d_ws;
  bf16* qbf = (bf16*)p; p += BSD * 2;
  bf16* kbf = (bf16*)p; p += BSD * 2;
  bf16* vbf = (bf16*)p; p += BSD * 2;
  bf16* qpb = (bf16*)p; p += BSD * 2;
  bf16* kpb = (bf16*)p; p += BSD * 2;
  bf16* vpb = (bf16*)p; p += BSD * 2;
  bf16* wqb = (bf16*)p; p += DD * 2;
  bf16* wkb = (bf16*)p; p += DD * 2;
  bf16* wvb = (bf16*)p; p += DD * 2;
  bf16* wob = (bf16*)p; p += DD * 2;
  bf16* vtb  = kbf;   // kbf dead after gemm_qkv
  bf16* ctxb = qbf;   // qbf dead after gemm_qkv

  // fold softmax scale (1/sqrt(64)=1/8) and log2(e) into Wq for exp2-domain softmax
  const float wq_scale = 0.125f * 1.4426950408889634f;

  cvt_qkv<<<dim3(1024, 1, 3), 256, 0, stream>>>(q, k, v, qbf, kbf, vbf, (int)(BSD / 4));
  cvt_w<<<dim3(256, 1, 4), 256, 0, stream>>>(Wq, Wk, Wv, Wo, wqb, wkb, wvb, wob,
                                             (int)(DD / 4), wq_scale);

  gemm_qkv<<<dim3(Dn / 128, (Bn * Sn) / 128, 3), 256, 0, stream>>>(
      qbf, wqb, qpb, kbf, wkb, kpb, vbf, wvb, vpb);

  transpose_bsd<<<dim3(Sn / 64, Dn / 64, Bn), 256, 0, stream>>>(vpb, vtb);

  flash_attn<<<dim3(1024), 128, 0, stream>>>(qpb, kpb, vtb, ctxb);

  gemm_out_f32<<<dim3(Dn / 128, (Bn * Sn) / 128), 256, 0, stream>>>(ctxb, wob, (float*)d_out);

  (void)in_sizes; (void)n_in; (void)out_size; (void)ws_size;
}

// Round 9
// 157.797 us; speedup vs baseline: 1.2134x; 1.0095x over previous
//
#include <hip/hip_runtime.h>

typedef __bf16 bf16;
typedef __bf16 bf16x4 __attribute__((ext_vector_type(4)));
typedef __bf16 bf16x8 __attribute__((ext_vector_type(8)));
typedef float f32x4 __attribute__((ext_vector_type(4)));
typedef float f32x16 __attribute__((ext_vector_type(16)));
typedef unsigned u32x4 __attribute__((ext_vector_type(4)));

static constexpr int Bn = 2, Sn = 2048, Dn = 1024, Hn = 16, HDn = 64;

__device__ __forceinline__ void gload_lds16(const void* g, void* l) {
  __builtin_amdgcn_global_load_lds((__attribute__((address_space(1))) void*)g,
                                   (__attribute__((address_space(3))) void*)l, 16, 0, 0);
}

__device__ __forceinline__ f32x4 mfma_bf16_16x16x32(bf16x8 a, bf16x8 b, f32x4 c) {
  return __builtin_amdgcn_mfma_f32_16x16x32_bf16(a, b, c, 0, 0, 0);
}

__device__ __forceinline__ f32x16 mfma_bf16_32x32x16(bf16x8 a, bf16x8 b, f32x16 c) {
  return __builtin_amdgcn_mfma_f32_32x32x16_bf16(a, b, c, 0, 0, 0);
}

__device__ __forceinline__ float fast_exp2(float x) {
  float r;
  asm("v_exp_f32 %0, %1" : "=v"(r) : "v"(x));
  return r;
}

__device__ __forceinline__ unsigned cvt_pk_bf16(float lo, float hi) {
  unsigned r;
  asm("v_cvt_pk_bf16_f32 %0, %1, %2" : "=v"(r) : "v"(lo), "v"(hi));
  return r;
}

// Cross-half (lane ^ 32) combine via known-good shfl_xor (ds_bpermute path).
__device__ __forceinline__ float cross_half_max(float v) {
  return fmaxf(v, __shfl_xor(v, 32, 64));
}
__device__ __forceinline__ float cross_half_add(float v) {
  return v + __shfl_xor(v, 32, 64);
}
__device__ __forceinline__ unsigned shfl32u(unsigned u) {
  return (unsigned)__shfl_xor((int)u, 32, 64);
}

#define WAITCNT_VM(N) asm volatile("s_waitcnt vmcnt(" #N ")" ::: "memory")
#define WAITCNT_LGKM0 asm volatile("s_waitcnt lgkmcnt(0)" ::: "memory")

// ---------------- fp32 -> bf16 convert for the 4 weight matrices ----------------
__global__ __launch_bounds__(256) void cvt_w(const float* __restrict__ a0,
                                             const float* __restrict__ a1,
                                             const float* __restrict__ a2,
                                             const float* __restrict__ a3,
                                             bf16* __restrict__ o0,
                                             bf16* __restrict__ o1,
                                             bf16* __restrict__ o2,
                                             bf16* __restrict__ o3,
                                             int n4, float s0) {
  const float* in; bf16* out; float s = 1.0f;
  switch (blockIdx.z) {
    case 0: in = a0; out = o0; s = s0; break;  // Wq gets softmax scale * log2(e)
    case 1: in = a1; out = o1; break;
    case 2: in = a2; out = o2; break;
    default: in = a3; out = o3; break;
  }
  int i = blockIdx.x * 256 + threadIdx.x;
  const int stride = gridDim.x * 256;
  for (; i < n4; i += stride) {
    float4 v = reinterpret_cast<const float4*>(in)[i];
    bf16x4 o;
    o[0] = (bf16)(v.x * s); o[1] = (bf16)(v.y * s);
    o[2] = (bf16)(v.z * s); o[3] = (bf16)(v.w * s);
    reinterpret_cast<bf16x4*>(out)[i] = o;
  }
}

// ---------------- GEMM: C[M,N] = A[M,K] * B[N,K]^T  (m97 structure) ----------------
// A may be f32 (converted to bf16 in-register during staging) or bf16 (gload_lds).
__device__ __forceinline__ void store_out(float* C, size_t i, float v) { C[i] = v; }
__device__ __forceinline__ void store_out(bf16* C, size_t i, float v) { C[i] = (bf16)v; }

template <typename AT, typename OutT>
__device__ __forceinline__ void gemm_bt_dev(const AT* __restrict__ A,
                                            const bf16* __restrict__ Bw,
                                            OutT* __restrict__ C,
                                            int K, int N) {
  const int t = threadIdx.x;
  const int l = t & 63, w = t >> 6;
  const int wr = w >> 1, wc = w & 1;
  const int lc = l & 15, lg = l >> 4;
  const int row0 = blockIdx.y * 128;
  const int col0 = blockIdx.x * 128;

  __shared__ bf16 As[128 * 32];
  __shared__ bf16 Bs[128 * 32];

  f32x4 acc[4][4] = {};

  for (int k0 = 0; k0 < K; k0 += 32) {
#pragma unroll
    for (int i = 0; i < 2; ++i) {
      const int c = i * 256 + t;          // 16B chunk id (bf16), 512 total
      const int r = c >> 2;               // tile row
      const int scc = (c & 3) ^ (r & 3);  // source chunk: XOR-swizzle
      gload_lds16(Bw + (size_t)(col0 + r) * K + k0 + scc * 8, Bs + c * 8);
      if constexpr (__is_same(AT, bf16)) {
        gload_lds16(A + (size_t)(row0 + r) * K + k0 + scc * 8, As + c * 8);
      } else {
        // fused f32 -> bf16 convert: reg-stage + ds_write (same resulting layout)
        const float* src = A + (size_t)(row0 + r) * K + k0 + scc * 8;
        const float4 f0 = *reinterpret_cast<const float4*>(src);
        const float4 f1 = *reinterpret_cast<const float4*>(src + 4);
        bf16x8 v8;
        v8[0] = (bf16)f0.x; v8[1] = (bf16)f0.y; v8[2] = (bf16)f0.z; v8[3] = (bf16)f0.w;
        v8[4] = (bf16)f1.x; v8[5] = (bf16)f1.y; v8[6] = (bf16)f1.z; v8[7] = (bf16)f1.w;
        *reinterpret_cast<bf16x8*>(As + c * 8) = v8;
      }
    }
    __syncthreads();  // drains vmcnt (gload_lds) + lgkmcnt (ds_write)

    bf16x8 af[4], bfr[4];
#pragma unroll
    for (int m = 0; m < 4; ++m) {
      const int r = wr * 64 + m * 16 + lc;
      af[m] = *reinterpret_cast<const bf16x8*>(As + r * 32 + ((lg ^ (r & 3)) * 8));
    }
#pragma unroll
    for (int n = 0; n < 4; ++n) {
      const int r = wc * 64 + n * 16 + lc;
      bfr[n] = *reinterpret_cast<const bf16x8*>(Bs + r * 32 + ((lg ^ (r & 3)) * 8));
    }
#pragma unroll
    for (int m = 0; m < 4; ++m)
#pragma unroll
      for (int n = 0; n < 4; ++n)
        acc[m][n] = mfma_bf16_16x16x32(af[m], bfr[n], acc[m][n]);
    __syncthreads();
  }

#pragma unroll
  for (int m = 0; m < 4; ++m) {
    const int rbase = row0 + wr * 64 + m * 16 + lg * 4;
#pragma unroll
    for (int n = 0; n < 4; ++n) {
      const int col = col0 + wc * 64 + n * 16 + lc;
#pragma unroll
      for (int j = 0; j < 4; ++j)
        store_out(C, (size_t)(rbase + j) * N + col, acc[m][n][j]);
    }
  }
}

__global__ __launch_bounds__(256) void gemm_qkv(
    const float* __restrict__ qa, const bf16* __restrict__ wq, bf16* __restrict__ qo,
    const float* __restrict__ ka, const bf16* __restrict__ wk, bf16* __restrict__ ko,
    const float* __restrict__ va, const bf16* __restrict__ wv, bf16* __restrict__ vo) {
  const float* A; const bf16* Bw; bf16* C;
  if (blockIdx.z == 0)      { A = qa; Bw = wq; C = qo; }
  else if (blockIdx.z == 1) { A = ka; Bw = wk; C = ko; }
  else                      { A = va; Bw = wv; C = vo; }
  gemm_bt_dev<float, bf16>(A, Bw, C, Dn, Dn);
}

__global__ __launch_bounds__(256) void gemm_out_f32(const bf16* __restrict__ A,
                                                    const bf16* __restrict__ Bw,
                                                    float* __restrict__ C) {
  gemm_bt_dev<bf16, float>(A, Bw, C, Dn, Dn);
}

// ---------------- per-batch transpose (S x D) -> (D x S) for V ----------------
__global__ __launch_bounds__(256) void transpose_bsd(const bf16* __restrict__ in,
                                                     bf16* __restrict__ out) {
  __shared__ bf16 tile[64][66];
  const int s0 = blockIdx.x * 64, d0 = blockIdx.y * 64, b = blockIdx.z;
  const int t = threadIdx.x;
#pragma unroll
  for (int i = 0; i < 2; ++i) {
    const int c = i * 256 + t;
    const int r = c >> 3, cc = (c & 7) * 8;
    const bf16x8 v = *reinterpret_cast<const bf16x8*>(
        in + ((size_t)b * Sn + s0 + r) * Dn + d0 + cc);
#pragma unroll
    for (int j = 0; j < 8; ++j) tile[r][cc + j] = v[j];
  }
  __syncthreads();
#pragma unroll
  for (int i = 0; i < 2; ++i) {
    const int c = i * 256 + t;
    const int r = c >> 3, cc = (c & 7) * 8;
    bf16x8 v;
#pragma unroll
    for (int j = 0; j < 8; ++j) v[j] = tile[cc + j][r];
    *reinterpret_cast<bf16x8*>(out + ((size_t)b * Dn + d0 + r) * Sn + s0 + cc) = v;
  }
}

// ---------------- causal flash attention (v7: paired qt, 4-wave, uniform blocks) ---------
// qp pre-scaled by (1/8)*log2(e) via Wq; softmax in exp2 domain.
// qp,kp: (B,S,D); vt: (B,D,S); ctx: (B,S,D)
// Block = 4 waves (QBLK=128, 32 rows/wave), KVBLK=64. Each block runs TWO phases:
// qtA = 15-pid (heavy) then qtB = pid -> exactly 34 tiles per block, all 256 blocks
// uniform -> occupancy holds steady (1 block/CU, 8 waves) with zero tail.
// XCD swizzle: XCD = n%8; g=(n&7)+8*(n>>6) pins each (h,b) K/V stream to one XCD
// (4 groups x 512KB = 2MB < 4MB L2/XCD). Bijective for 256 = 8x4x8.
// LDS 40KB: K dbuf (j&1) 2x8KB, V tri-buf (j%3) 3x8KB; epilogue slab 18KB aliases
// K + head of V[0], protected by a post-loop barrier.
__global__ __launch_bounds__(256) void flash_attn(const bf16* __restrict__ qp,
                                                  const bf16* __restrict__ kp,
                                                  const bf16* __restrict__ vt,
                                                  bf16* __restrict__ ctx) {
  const int n = blockIdx.x;
  const int g = (n & 7) + 8 * (n >> 6);
  const int pid = (n >> 3) & 7;
  const int h = g & 15;
  const int b = g >> 4;
  const int t = threadIdx.x, w = t >> 6, l = t & 63;
  const int lq = l & 31, hi = l >> 5;

  __shared__ char smem[40960];

  // staging: 2 K-chunks + 2 V-chunks per thread (256 threads x 16B x 2 = 8KB tile)
  // chunk c = i*256 + t -> row r = i*32 + (t>>3); scc = (t&7)^((t>>3)&7) (i-invariant)
  const int rl = t >> 3;
  const int scc = (t & 7) ^ (rl & 7);
  const bf16* kbase = kp + ((size_t)b * Sn + rl) * Dn + h * HDn + scc * 8;
  const bf16* vbase = vt + ((size_t)b * Dn + h * HDn + rl) * Sn + scc * 8;

  auto STAGE = [&](int j) {  // stage KV tile j (4 gload_lds)
    const int kv0 = j * 64;
    char* Kd = smem + (j & 1) * 8192 + t * 16;
    char* Vd = smem + 16384 + (j % 3) * 8192 + t * 16;
    const bf16* ks = kbase + (size_t)kv0 * Dn;
    const bf16* vs = vbase + kv0;
#pragma unroll
    for (int i = 0; i < 2; ++i) {
      gload_lds16(ks + (size_t)i * 32 * Dn, Kd + i * 4096);
      gload_lds16(vs + (size_t)i * 32 * Sn, Vd + i * 4096);
    }
  };

  int qrow0 = 0;
  bf16x8 qf[4];
  f32x16 oacc0, oacc1;
  float mrow, lsum;

  auto QK = [&](int j, f32x16& s0_, f32x16& s1_) {
    const char* Kc = smem + (j & 1) * 8192;
    __builtin_amdgcn_s_setprio(1);
#pragma unroll
    for (int kk = 0; kk < 4; ++kk) {
      const int ch = kk * 2 + hi;
      const int r0 = lq, r1 = 32 + lq;
      const bf16x8 k0 = *reinterpret_cast<const bf16x8*>(Kc + r0 * 128 + ((ch ^ (r0 & 7)) << 4));
      const bf16x8 k1 = *reinterpret_cast<const bf16x8*>(Kc + r1 * 128 + ((ch ^ (r1 & 7)) << 4));
      s0_ = mfma_bf16_32x32x16(k0, qf[kk], s0_);
      s1_ = mfma_bf16_32x32x16(k1, qf[kk], s1_);
    }
    __builtin_amdgcn_s_setprio(0);
  };

  auto SMPV = [&](int j, f32x16& s0, f32x16& s1) {
    const int kv0 = j * 64;
    const char* Vc = smem + 16384 + (j % 3) * 8192;

    if (kv0 + 63 > qrow0) {  // causal mask (diagonal-crossing tiles only)
      const int qg = qrow0 + lq;
#pragma unroll
      for (int r = 0; r < 16; ++r) {
        const int kvl = (r & 3) + 8 * (r >> 2) + 4 * hi;
        if (kv0 + kvl > qg)      s0[r] = -1e30f;
        if (kv0 + 32 + kvl > qg) s1[r] = -1e30f;
      }
    }

    float mx[8];
#pragma unroll
    for (int i = 0; i < 8; ++i)
      mx[i] = fmaxf(fmaxf(s0[i], s0[i + 8]), fmaxf(s1[i], s1[i + 8]));
#pragma unroll
    for (int i = 0; i < 4; ++i) mx[i] = fmaxf(mx[i], mx[i + 4]);
    const float tmax_own = fmaxf(fmaxf(mx[0], mx[1]), fmaxf(mx[2], mx[3]));
    const float tmax = cross_half_max(tmax_own);  // pair-uniform over {lq, lq+32}

    float alpha = 1.0f;
    if (!__all(tmax <= mrow + 8.0f)) {  // defer-max (T13): wave-uniform rescale
      const float mn = fmaxf(mrow, tmax);
      alpha = fast_exp2(mrow - mn);
      mrow = mn;
#pragma unroll
      for (int r = 0; r < 16; ++r) { oacc0[r] *= alpha; oacc1[r] *= alpha; }
    }
#pragma unroll
    for (int r = 0; r < 16; ++r) {
      s0[r] = fast_exp2(s0[r] - mrow);  // bounded by 2^8 when deferred
      s1[r] = fast_exp2(s1[r] - mrow);
    }
    float sm[8];
#pragma unroll
    for (int i = 0; i < 8; ++i)
      sm[i] = (s0[i] + s0[i + 8]) + (s1[i] + s1[i + 8]);
#pragma unroll
    for (int i = 0; i < 4; ++i) sm[i] += sm[i + 4];
    float rsum = (sm[0] + sm[1]) + (sm[2] + sm[3]);
    rsum = cross_half_add(rsum);
    lsum = lsum * alpha + rsum;

    // P -> bf16 B-fragments; cross-half exchange with 2 shfl per c2
    // (select-before-shfl: y1 = hi?u0:u2 -> partner delivers p0 (hi=0) / p2 (hi=1);
    //  y2 = hi?u1:u3 -> p1 / p3)
    u32x4 pw[4];
#pragma unroll
    for (int c2 = 0; c2 < 4; ++c2) {
      const f32x16& S = (c2 < 2) ? s0 : s1;
      const int base = (c2 & 1) * 8;
      const unsigned u0 = cvt_pk_bf16(S[base + 0], S[base + 1]);
      const unsigned u1 = cvt_pk_bf16(S[base + 2], S[base + 3]);
      const unsigned u2 = cvt_pk_bf16(S[base + 4], S[base + 5]);
      const unsigned u3 = cvt_pk_bf16(S[base + 6], S[base + 7]);
      const unsigned r1 = shfl32u(hi ? u0 : u2);
      const unsigned r2 = shfl32u(hi ? u1 : u3);
      pw[c2][0] = hi ? r1 : u0;
      pw[c2][1] = hi ? r2 : u1;
      pw[c2][2] = hi ? u2 : r1;
      pw[c2][3] = hi ? u3 : r2;
    }

    __builtin_amdgcn_s_setprio(1);
#pragma unroll
    for (int kk = 0; kk < 4; ++kk) {
      const bf16x8 pf = __builtin_bit_cast(bf16x8, pw[kk]);
      const int ch = kk * 2 + hi;
      const int r0 = lq, r1 = 32 + lq;
      const bf16x8 v0 = *reinterpret_cast<const bf16x8*>(Vc + r0 * 128 + ((ch ^ (r0 & 7)) << 4));
      const bf16x8 v1 = *reinterpret_cast<const bf16x8*>(Vc + r1 * 128 + ((ch ^ (r1 & 7)) << 4));
      oacc0 = mfma_bf16_32x32x16(v0, pf, oacc0);
      oacc1 = mfma_bf16_32x32x16(v1, pf, oacc1);
    }
    __builtin_amdgcn_s_setprio(0);
  };

  for (int ph = 0; ph < 2; ++ph) {
    const int qt = ph ? pid : 15 - pid;  // heavy phase first
    qrow0 = qt * 128 + w * 32;
    const int nkv = 2 * qt + 2;

#pragma unroll
    for (int kk = 0; kk < 4; ++kk)
      qf[kk] = *reinterpret_cast<const bf16x8*>(
          qp + ((size_t)b * Sn + qrow0 + lq) * Dn + h * HDn + kk * 16 + hi * 8);
    oacc0 = f32x16{}; oacc1 = f32x16{};
    mrow = -1e30f; lsum = 0.0f;

    // phase-top barrier: all prior-phase epilogue LDS reads retired before STAGE writes
    __builtin_amdgcn_s_barrier();
    __builtin_amdgcn_sched_barrier(0);
    STAGE(0);
    STAGE(1);  // nkv >= 2 always
    WAITCNT_VM(4);
    __builtin_amdgcn_sched_barrier(0);
    __builtin_amdgcn_s_barrier();
    __builtin_amdgcn_sched_barrier(0);

    f32x16 sp0 = {}, sp1 = {};
    QK(0, sp0, sp1);

    for (int kt = 0; kt < nkv; ++kt) {
      WAITCNT_VM(0);
      __builtin_amdgcn_sched_barrier(0);
      __builtin_amdgcn_s_barrier();
      __builtin_amdgcn_sched_barrier(0);

      if (kt + 2 < nkv) STAGE(kt + 2);
      f32x16 sn0 = {}, sn1 = {};
      if (kt + 1 < nkv && (kt + 1) * 64 <= qrow0 + 31)
        QK(kt + 1, sn0, sn1);              // MFMA, overlaps softmax(kt) below
      if (kt * 64 <= qrow0 + 31)
        SMPV(kt, sp0, sp1);                // VALU-heavy + PV MFMA
      sp0 = sn0; sp1 = sn1;
      WAITCNT_LGKM0;
    }

    // all waves done reading K/V before epilogue slab writes (slab spans 18KB)
    __builtin_amdgcn_s_barrier();
    __builtin_amdgcn_sched_barrier(0);

    const float inv = 1.0f / lsum;
    bf16* ep = (bf16*)(smem + w * 4608);  // [32 q][72 d] bf16 per wave
#pragma unroll
    for (int dt = 0; dt < 2; ++dt) {
      const f32x16& O = dt ? oacc1 : oacc0;
#pragma unroll
      for (int g2 = 0; g2 < 4; ++g2) {
        bf16x4 o4;
#pragma unroll
        for (int j = 0; j < 4; ++j) o4[j] = (bf16)(O[g2 * 4 + j] * inv);
        const int d = dt * 32 + g2 * 8 + hi * 4;
        *reinterpret_cast<bf16x4*>(&ep[lq * 72 + d]) = o4;
      }
    }
    WAITCNT_LGKM0;
    __builtin_amdgcn_sched_barrier(0);
#pragma unroll
    for (int i = 0; i < 4; ++i) {
      const int q = i * 8 + (l >> 3);
      const int d0 = (l & 7) * 8;
      const bf16x8 vv = *reinterpret_cast<const bf16x8*>(&ep[q * 72 + d0]);
      *reinterpret_cast<bf16x8*>(
          &ctx[((size_t)b * Sn + qrow0 - w * 32 + w * 32 + q) * Dn + h * HDn + d0]) = vv;
    }
  }
}

// ---------------- launch ----------------
extern "C" void kernel_launch(void* const* d_in, const int* in_sizes, int n_in,
                              void* d_out, int out_size, void* d_ws, size_t ws_size,
                              hipStream_t stream) {
  const float* q  = (const float*)d_in[0];
  const float* k  = (const float*)d_in[1];
  const float* v  = (const float*)d_in[2];
  // d_in[3] = causal mask (structure known; unused)
  const float* Wq = (const float*)d_in[4];
  const float* Wk = (const float*)d_in[5];
  const float* Wv = (const float*)d_in[6];
  const float* Wo = (const float*)d_in[7];

  constexpr size_t BSD = (size_t)Bn * Sn * Dn;
  constexpr size_t DD  = (size_t)Dn * Dn;

  char* p = (char*)d_ws;
  bf16* qbf = (bf16*)p; p += BSD * 2;  // region reused as ctx
  bf16* kbf = (bf16*)p; p += BSD * 2;  // region reused as vt
  p += BSD * 2;                        // (formerly vbf; unused)
  bf16* qpb = (bf16*)p; p += BSD * 2;
  bf16* kpb = (bf16*)p; p += BSD * 2;
  bf16* vpb = (bf16*)p; p += BSD * 2;
  bf16* wqb = (bf16*)p; p += DD * 2;
  bf16* wkb = (bf16*)p; p += DD * 2;
  bf16* wvb = (bf16*)p; p += DD * 2;
  bf16* wob = (bf16*)p; p += DD * 2;
  bf16* vtb  = kbf;
  bf16* ctxb = qbf;

  // fold softmax scale (1/sqrt(64)=1/8) and log2(e) into Wq for exp2-domain softmax
  const float wq_scale = 0.125f * 1.4426950408889634f;

  cvt_w<<<dim3(256, 1, 4), 256, 0, stream>>>(Wq, Wk, Wv, Wo, wqb, wkb, wvb, wob,
                                             (int)(DD / 4), wq_scale);

  gemm_qkv<<<dim3(Dn / 128, (Bn * Sn) / 128, 3), 256, 0, stream>>>(
      q, wqb, qpb, k, wkb, kpb, v, wvb, vpb);

  transpose_bsd<<<dim3(Sn / 64, Dn / 64, Bn), 256, 0, stream>>>(vpb, vtb);

  flash_attn<<<dim3(256), 256, 0, stream>>>(qpb, kpb, vtb, ctxb);

  gemm_out_f32<<<dim3(Dn / 128, (Bn * Sn) / 128), 256, 0, stream>>>(ctxb, wob, (float*)d_out);

  (void)in_sizes; (void)n_in; (void)out_size; (void)ws_size;
}

// Round 11
// 143.865 us; speedup vs baseline: 1.3309x; 1.0968x over previous
//
#include <hip/hip_runtime.h>

typedef __bf16 bf16;
typedef __bf16 bf16x4 __attribute__((ext_vector_type(4)));
typedef __bf16 bf16x8 __attribute__((ext_vector_type(8)));
typedef float f32x4 __attribute__((ext_vector_type(4)));
typedef float f32x16 __attribute__((ext_vector_type(16)));
typedef unsigned u32x4 __attribute__((ext_vector_type(4)));

static constexpr int Bn = 2, Sn = 2048, Dn = 1024, Hn = 16, HDn = 64;

__device__ __forceinline__ void gload_lds16(const void* g, void* l) {
  __builtin_amdgcn_global_load_lds((__attribute__((address_space(1))) void*)g,
                                   (__attribute__((address_space(3))) void*)l, 16, 0, 0);
}

__device__ __forceinline__ f32x4 mfma_bf16_16x16x32(bf16x8 a, bf16x8 b, f32x4 c) {
  return __builtin_amdgcn_mfma_f32_16x16x32_bf16(a, b, c, 0, 0, 0);
}

__device__ __forceinline__ f32x16 mfma_bf16_32x32x16(bf16x8 a, bf16x8 b, f32x16 c) {
  return __builtin_amdgcn_mfma_f32_32x32x16_bf16(a, b, c, 0, 0, 0);
}

__device__ __forceinline__ float fast_exp2(float x) {
  float r;
  asm("v_exp_f32 %0, %1" : "=v"(r) : "v"(x));
  return r;
}

__device__ __forceinline__ unsigned cvt_pk_bf16(float lo, float hi) {
  unsigned r;
  asm("v_cvt_pk_bf16_f32 %0, %1, %2" : "=v"(r) : "v"(lo), "v"(hi));
  return r;
}

// Cross-half (lane ^ 32) combine via known-good shfl_xor (ds_bpermute path).
__device__ __forceinline__ float cross_half_max(float v) {
  return fmaxf(v, __shfl_xor(v, 32, 64));
}
__device__ __forceinline__ float cross_half_add(float v) {
  return v + __shfl_xor(v, 32, 64);
}
__device__ __forceinline__ unsigned shfl32u(unsigned u) {
  return (unsigned)__shfl_xor((int)u, 32, 64);
}

#define WAITCNT_VM(N) asm volatile("s_waitcnt vmcnt(" #N ")" ::: "memory")
#define WAITCNT_LGKM0 asm volatile("s_waitcnt lgkmcnt(0)" ::: "memory")

// ---------------- fp32 -> bf16 converts (fused launches) ----------------
__global__ __launch_bounds__(256) void cvt_qkv(const float* __restrict__ a0,
                                               const float* __restrict__ a1,
                                               const float* __restrict__ a2,
                                               bf16* __restrict__ o0,
                                               bf16* __restrict__ o1,
                                               bf16* __restrict__ o2, int n4) {
  const float* in = blockIdx.z == 0 ? a0 : (blockIdx.z == 1 ? a1 : a2);
  bf16* out = blockIdx.z == 0 ? o0 : (blockIdx.z == 1 ? o1 : o2);
  int i = blockIdx.x * 256 + threadIdx.x;
  const int stride = gridDim.x * 256;
  for (; i < n4; i += stride) {
    float4 v = reinterpret_cast<const float4*>(in)[i];
    bf16x4 o;
    o[0] = (bf16)v.x; o[1] = (bf16)v.y; o[2] = (bf16)v.z; o[3] = (bf16)v.w;
    reinterpret_cast<bf16x4*>(out)[i] = o;
  }
}

__global__ __launch_bounds__(256) void cvt_w(const float* __restrict__ a0,
                                             const float* __restrict__ a1,
                                             const float* __restrict__ a2,
                                             const float* __restrict__ a3,
                                             bf16* __restrict__ o0,
                                             bf16* __restrict__ o1,
                                             bf16* __restrict__ o2,
                                             bf16* __restrict__ o3,
                                             int n4, float s0) {
  const float* in; bf16* out; float s = 1.0f;
  switch (blockIdx.z) {
    case 0: in = a0; out = o0; s = s0; break;  // Wq gets softmax scale * log2(e)
    case 1: in = a1; out = o1; break;
    case 2: in = a2; out = o2; break;
    default: in = a3; out = o3; break;
  }
  int i = blockIdx.x * 256 + threadIdx.x;
  const int stride = gridDim.x * 256;
  for (; i < n4; i += stride) {
    float4 v = reinterpret_cast<const float4*>(in)[i];
    bf16x4 o;
    o[0] = (bf16)(v.x * s); o[1] = (bf16)(v.y * s);
    o[2] = (bf16)(v.z * s); o[3] = (bf16)(v.w * s);
    reinterpret_cast<bf16x4*>(out)[i] = o;
  }
}

// ---------------- GEMM: C[M,N] = A[M,K] * B[N,K]^T  (m97 structure, bf16 A) -------------
__device__ __forceinline__ void store_out(float* C, size_t i, float v) { C[i] = v; }
__device__ __forceinline__ void store_out(bf16* C, size_t i, float v) { C[i] = (bf16)v; }

template <typename OutT>
__device__ __forceinline__ void gemm_bt_dev(const bf16* __restrict__ A,
                                            const bf16* __restrict__ Bw,
                                            OutT* __restrict__ C,
                                            int K, int N) {
  const int t = threadIdx.x;
  const int l = t & 63, w = t >> 6;
  const int wr = w >> 1, wc = w & 1;
  const int lc = l & 15, lg = l >> 4;
  const int row0 = blockIdx.y * 128;
  const int col0 = blockIdx.x * 128;

  __shared__ bf16 As[128 * 32];
  __shared__ bf16 Bs[128 * 32];

  f32x4 acc[4][4] = {};

  for (int k0 = 0; k0 < K; k0 += 32) {
#pragma unroll
    for (int i = 0; i < 2; ++i) {
      const int c = i * 256 + t;
      const int r = c >> 2;
      const int scc = (c & 3) ^ (r & 3);
      gload_lds16(A + (size_t)(row0 + r) * K + k0 + scc * 8, As + c * 8);
      gload_lds16(Bw + (size_t)(col0 + r) * K + k0 + scc * 8, Bs + c * 8);
    }
    __syncthreads();

    bf16x8 af[4], bfr[4];
#pragma unroll
    for (int m = 0; m < 4; ++m) {
      const int r = wr * 64 + m * 16 + lc;
      af[m] = *reinterpret_cast<const bf16x8*>(As + r * 32 + ((lg ^ (r & 3)) * 8));
    }
#pragma unroll
    for (int n = 0; n < 4; ++n) {
      const int r = wc * 64 + n * 16 + lc;
      bfr[n] = *reinterpret_cast<const bf16x8*>(Bs + r * 32 + ((lg ^ (r & 3)) * 8));
    }
#pragma unroll
    for (int m = 0; m < 4; ++m)
#pragma unroll
      for (int n = 0; n < 4; ++n)
        acc[m][n] = mfma_bf16_16x16x32(af[m], bfr[n], acc[m][n]);
    __syncthreads();
  }

#pragma unroll
  for (int m = 0; m < 4; ++m) {
    const int rbase = row0 + wr * 64 + m * 16 + lg * 4;
#pragma unroll
    for (int n = 0; n < 4; ++n) {
      const int col = col0 + wc * 64 + n * 16 + lc;
#pragma unroll
      for (int j = 0; j < 4; ++j)
        store_out(C, (size_t)(rbase + j) * N + col, acc[m][n][j]);
    }
  }
}

__global__ __launch_bounds__(256) void gemm_qkv(
    const bf16* __restrict__ qa, const bf16* __restrict__ wq, bf16* __restrict__ qo,
    const bf16* __restrict__ ka, const bf16* __restrict__ wk, bf16* __restrict__ ko,
    const bf16* __restrict__ va, const bf16* __restrict__ wv, bf16* __restrict__ vo) {
  const bf16 *A, *Bw;
  bf16* C;
  if (blockIdx.z == 0)      { A = qa; Bw = wq; C = qo; }
  else if (blockIdx.z == 1) { A = ka; Bw = wk; C = ko; }
  else                      { A = va; Bw = wv; C = vo; }
  gemm_bt_dev<bf16>(A, Bw, C, Dn, Dn);
}

__global__ __launch_bounds__(256) void gemm_out_f32(const bf16* __restrict__ A,
                                                    const bf16* __restrict__ Bw,
                                                    float* __restrict__ C) {
  gemm_bt_dev<float>(A, Bw, C, Dn, Dn);
}

// ---------------- per-batch transpose (S x D) -> (D x S) for V ----------------
__global__ __launch_bounds__(256) void transpose_bsd(const bf16* __restrict__ in,
                                                     bf16* __restrict__ out) {
  __shared__ bf16 tile[64][66];
  const int s0 = blockIdx.x * 64, d0 = blockIdx.y * 64, b = blockIdx.z;
  const int t = threadIdx.x;
#pragma unroll
  for (int i = 0; i < 2; ++i) {
    const int c = i * 256 + t;
    const int r = c >> 3, cc = (c & 7) * 8;
    const bf16x8 v = *reinterpret_cast<const bf16x8*>(
        in + ((size_t)b * Sn + s0 + r) * Dn + d0 + cc);
#pragma unroll
    for (int j = 0; j < 8; ++j) tile[r][cc + j] = v[j];
  }
  __syncthreads();
#pragma unroll
  for (int i = 0; i < 2; ++i) {
    const int c = i * 256 + t;
    const int r = c >> 3, cc = (c & 7) * 8;
    bf16x8 v;
#pragma unroll
    for (int j = 0; j < 8; ++j) v[j] = tile[cc + j][r];
    *reinterpret_cast<bf16x8*>(out + ((size_t)b * Dn + d0 + r) * Sn + s0 + cc) = v;
  }
}

// ---------------- causal flash attention (v8b: in-block KV-split, race-fixed) ------------
// Identical to v8 (R10) except ONE added barrier: the chunk1 partial-publish writes
// land in chunk0's staging region, so an s_barrier must separate the chunk loop's
// final K/V reads from those writes. R10 lacked it -> half1's f32 Op writes corrupted
// half0's in-flight bf16 K/V reads (f32 fragments decode as Inf/NaN bf16) -> NaN.
__global__ __launch_bounds__(512) void flash_attn(const bf16* __restrict__ qp,
                                                  const bf16* __restrict__ kp,
                                                  const bf16* __restrict__ vt,
                                                  bf16* __restrict__ ctx) {
  const int n = blockIdx.x;
  const int j = n >> 3;
  const int g = (n & 7) + 8 * (j >> 4);
  const int qt = 15 - (j & 15);
  const int h = g & 15;
  const int b = g >> 4;
  const int t = threadIdx.x, w = t >> 6, l = t & 63;
  const int lq = l & 31, hi = l >> 5;
  const int half = w >> 2;             // 0: chunk0 waves, 1: chunk1 waves
  const int qrow0 = qt * 128 + (w & 3) * 32;
  const int cnt = qt + 1;              // tiles per chunk
  const int tbase = half * cnt;        // first (global) tile index of my chunk

  __shared__ char smem[81920];
  char* my = smem + half * 40960;      // my half's staging region

  // staging: 256 threads per half; 2 K-chunks + 2 V-chunks per thread per tile
  const int tl = t & 255;
  const int rl = tl >> 3;
  const int scc = (tl & 7) ^ (rl & 7);
  const bf16* kbase = kp + ((size_t)b * Sn + rl) * Dn + h * HDn + scc * 8;
  const bf16* vbase = vt + ((size_t)b * Dn + h * HDn + rl) * Sn + scc * 8;

  auto STAGE = [&](int i) {  // local tile i of my chunk (4 gload_lds / thread)
    const int kv0 = (tbase + i) * 64;
    char* Kd = my + (i & 1) * 8192 + tl * 16;
    char* Vd = my + 16384 + (i % 3) * 8192 + tl * 16;
    const bf16* ks = kbase + (size_t)kv0 * Dn;
    const bf16* vs = vbase + kv0;
#pragma unroll
    for (int ii = 0; ii < 2; ++ii) {
      gload_lds16(ks + (size_t)ii * 32 * Dn, Kd + ii * 4096);
      gload_lds16(vs + (size_t)ii * 32 * Sn, Vd + ii * 4096);
    }
  };

  // Q fragments (B-operand of swapped QK^T): lane holds q=lq, k = kk*16 + hi*8 + e
  bf16x8 qf[4];
#pragma unroll
  for (int kk = 0; kk < 4; ++kk)
    qf[kk] = *reinterpret_cast<const bf16x8*>(
        qp + ((size_t)b * Sn + qrow0 + lq) * Dn + h * HDn + kk * 16 + hi * 8);

  f32x16 oacc0 = {}, oacc1 = {};  // O^T partial: d 0..31 / 32..63 (per-reg), q = lq
  float mrow = -1e30f, lsum = 0.0f;

  auto QK = [&](int i, f32x16& s0_, f32x16& s1_) {
    const char* Kc = my + (i & 1) * 8192;
    __builtin_amdgcn_s_setprio(1);
#pragma unroll
    for (int kk = 0; kk < 4; ++kk) {
      const int ch = kk * 2 + hi;
      const int r0 = lq, r1 = 32 + lq;
      const bf16x8 k0 = *reinterpret_cast<const bf16x8*>(Kc + r0 * 128 + ((ch ^ (r0 & 7)) << 4));
      const bf16x8 k1 = *reinterpret_cast<const bf16x8*>(Kc + r1 * 128 + ((ch ^ (r1 & 7)) << 4));
      s0_ = mfma_bf16_32x32x16(k0, qf[kk], s0_);
      s1_ = mfma_bf16_32x32x16(k1, qf[kk], s1_);
    }
    __builtin_amdgcn_s_setprio(0);
  };

  auto SMPV = [&](int i, f32x16& s0, f32x16& s1) {
    const int kv0 = (tbase + i) * 64;
    const char* Vc = my + 16384 + (i % 3) * 8192;

    if (kv0 + 63 > qrow0) {  // causal mask (diagonal-crossing tiles only)
      const int qg = qrow0 + lq;
#pragma unroll
      for (int r = 0; r < 16; ++r) {
        const int kvl = (r & 3) + 8 * (r >> 2) + 4 * hi;
        if (kv0 + kvl > qg)      s0[r] = -1e30f;
        if (kv0 + 32 + kvl > qg) s1[r] = -1e30f;
      }
    }

    float mx[8];
#pragma unroll
    for (int i2 = 0; i2 < 8; ++i2)
      mx[i2] = fmaxf(fmaxf(s0[i2], s0[i2 + 8]), fmaxf(s1[i2], s1[i2 + 8]));
#pragma unroll
    for (int i2 = 0; i2 < 4; ++i2) mx[i2] = fmaxf(mx[i2], mx[i2 + 4]);
    const float tmax_own = fmaxf(fmaxf(mx[0], mx[1]), fmaxf(mx[2], mx[3]));
    const float tmax = cross_half_max(tmax_own);  // pair-uniform over {lq, lq+32}

    float alpha = 1.0f;
    if (!__all(tmax <= mrow + 8.0f)) {  // defer-max (T13): wave-uniform rescale
      const float mn = fmaxf(mrow, tmax);
      alpha = fast_exp2(mrow - mn);
      mrow = mn;
#pragma unroll
      for (int r = 0; r < 16; ++r) { oacc0[r] *= alpha; oacc1[r] *= alpha; }
    }
#pragma unroll
    for (int r = 0; r < 16; ++r) {
      s0[r] = fast_exp2(s0[r] - mrow);  // bounded by 2^8 when deferred
      s1[r] = fast_exp2(s1[r] - mrow);
    }
    float sm[8];
#pragma unroll
    for (int i2 = 0; i2 < 8; ++i2)
      sm[i2] = (s0[i2] + s0[i2 + 8]) + (s1[i2] + s1[i2 + 8]);
#pragma unroll
    for (int i2 = 0; i2 < 4; ++i2) sm[i2] += sm[i2 + 4];
    float rsum = (sm[0] + sm[1]) + (sm[2] + sm[3]);
    rsum = cross_half_add(rsum);
    lsum = lsum * alpha + rsum;

    // P -> bf16 B-fragments; cross-half exchange with 2 shfl per c2
    u32x4 pw[4];
#pragma unroll
    for (int c2 = 0; c2 < 4; ++c2) {
      const f32x16& S = (c2 < 2) ? s0 : s1;
      const int base = (c2 & 1) * 8;
      const unsigned u0 = cvt_pk_bf16(S[base + 0], S[base + 1]);
      const unsigned u1 = cvt_pk_bf16(S[base + 2], S[base + 3]);
      const unsigned u2 = cvt_pk_bf16(S[base + 4], S[base + 5]);
      const unsigned u3 = cvt_pk_bf16(S[base + 6], S[base + 7]);
      const unsigned r1 = shfl32u(hi ? u0 : u2);
      const unsigned r2 = shfl32u(hi ? u1 : u3);
      pw[c2][0] = hi ? r1 : u0;
      pw[c2][1] = hi ? r2 : u1;
      pw[c2][2] = hi ? u2 : r1;
      pw[c2][3] = hi ? u3 : r2;
    }

    __builtin_amdgcn_s_setprio(1);
#pragma unroll
    for (int kk = 0; kk < 4; ++kk) {
      const bf16x8 pf = __builtin_bit_cast(bf16x8, pw[kk]);
      const int ch = kk * 2 + hi;
      const int r0 = lq, r1 = 32 + lq;
      const bf16x8 v0 = *reinterpret_cast<const bf16x8*>(Vc + r0 * 128 + ((ch ^ (r0 & 7)) << 4));
      const bf16x8 v1 = *reinterpret_cast<const bf16x8*>(Vc + r1 * 128 + ((ch ^ (r1 & 7)) << 4));
      oacc0 = mfma_bf16_32x32x16(v0, pf, oacc0);
      oacc1 = mfma_bf16_32x32x16(v1, pf, oacc1);
    }
    __builtin_amdgcn_s_setprio(0);
  };

  // ---- pipelined chunk loop (cnt tiles) ----
  STAGE(0);
  if (cnt > 1) { STAGE(1); WAITCNT_VM(4); } else { WAITCNT_VM(0); }
  __builtin_amdgcn_sched_barrier(0);
  __builtin_amdgcn_s_barrier();
  __builtin_amdgcn_sched_barrier(0);

  f32x16 sp0 = {}, sp1 = {};
  if (tbase * 64 <= qrow0 + 31) QK(0, sp0, sp1);

  for (int i = 0; i < cnt; ++i) {
    WAITCNT_VM(0);
    __builtin_amdgcn_sched_barrier(0);
    __builtin_amdgcn_s_barrier();
    __builtin_amdgcn_sched_barrier(0);

    if (i + 2 < cnt) STAGE(i + 2);
    f32x16 sn0 = {}, sn1 = {};
    if (i + 1 < cnt && (tbase + i + 1) * 64 <= qrow0 + 31) QK(i + 1, sn0, sn1);
    if ((tbase + i) * 64 <= qrow0 + 31) SMPV(i, sp0, sp1);
    sp0 = sn0; sp1 = sn1;
    WAITCNT_LGKM0;
  }

  // ---- RACE FIX (R10 bug): quiesce ALL waves' staging-region reads before the
  // publish below overwrites chunk0's K/V bytes with f32 partials.
  __builtin_amdgcn_s_barrier();
  __builtin_amdgcn_sched_barrier(0);

  // ---- merge: chunk1 publishes partials via LDS (staging regions now dead) ----
  // Op: [128 rows][65 d-stride] f32 (33280B) at smem+0; Ml: m[128], l[128] at +33280.
  float* Op = (float*)smem;
  float* Ml = (float*)(smem + 33280);
  const int lrow = (w & 3) * 32 + lq;

  if (half == 1) {
#pragma unroll
    for (int r = 0; r < 16; ++r) {
      const int d = (r & 3) + 8 * (r >> 2) + 4 * hi;
      Op[lrow * 65 + d]      = oacc0[r];
      Op[lrow * 65 + 32 + d] = oacc1[r];
    }
    if (hi == 0) { Ml[lrow] = mrow; Ml[128 + lrow] = lsum; }
  }
  WAITCNT_LGKM0;
  __builtin_amdgcn_s_barrier();
  __builtin_amdgcn_sched_barrier(0);

  if (half == 0) {
    const float m1 = Ml[lrow], l1 = Ml[128 + lrow];
    const float m  = fmaxf(mrow, m1);
    const float a0 = fast_exp2(mrow - m);
    const float a1 = fast_exp2(m1 - m);
    const float inv = 1.0f / (lsum * a0 + l1 * a1);

    // merged O -> per-wave slab (half1 staging region, dead) -> coalesced stores
    bf16* ep = (bf16*)(smem + 40960 + w * 4608);  // [32 q][72 d] bf16
#pragma unroll
    for (int dt = 0; dt < 2; ++dt) {
      const f32x16& O = dt ? oacc1 : oacc0;
#pragma unroll
      for (int g2 = 0; g2 < 4; ++g2) {
        bf16x4 o4;
#pragma unroll
        for (int jj = 0; jj < 4; ++jj) {
          const int d = dt * 32 + 8 * g2 + 4 * hi + jj;
          const float o1 = Op[lrow * 65 + d];
          o4[jj] = (bf16)((O[g2 * 4 + jj] * a0 + o1 * a1) * inv);
        }
        const int d0 = dt * 32 + g2 * 8 + hi * 4;
        *reinterpret_cast<bf16x4*>(&ep[lq * 72 + d0]) = o4;
      }
    }
    WAITCNT_LGKM0;
    __builtin_amdgcn_sched_barrier(0);
#pragma unroll
    for (int i = 0; i < 4; ++i) {
      const int q = i * 8 + (l >> 3);
      const int d0 = (l & 7) * 8;
      const bf16x8 vv = *reinterpret_cast<const bf16x8*>(&ep[q * 72 + d0]);
      *reinterpret_cast<bf16x8*>(
          &ctx[((size_t)b * Sn + qrow0 + q) * Dn + h * HDn + d0]) = vv;
    }
  }
}

// ---------------- launch ----------------
extern "C" void kernel_launch(void* const* d_in, const int* in_sizes, int n_in,
                              void* d_out, int out_size, void* d_ws, size_t ws_size,
                              hipStream_t stream) {
  const float* q  = (const float*)d_in[0];
  const float* k  = (const float*)d_in[1];
  const float* v  = (const float*)d_in[2];
  // d_in[3] = causal mask (structure known; unused)
  const float* Wq = (const float*)d_in[4];
  const float* Wk = (const float*)d_in[5];
  const float* Wv = (const float*)d_in[6];
  const float* Wo = (const float*)d_in[7];

  constexpr size_t BSD = (size_t)Bn * Sn * Dn;
  constexpr size_t DD  = (size_t)Dn * Dn;

  char* p = (char*)d_ws;
  bf16* qbf = (bf16*)p; p += BSD * 2;  // reused as ctx after gemm_qkv
  bf16* kbf = (bf16*)p; p += BSD * 2;  // reused as vt  after gemm_qkv
  bf16* vbf = (bf16*)p; p += BSD * 2;
  bf16* qpb = (bf16*)p; p += BSD * 2;
  bf16* kpb = (bf16*)p; p += BSD * 2;
  bf16* vpb = (bf16*)p; p += BSD * 2;
  bf16* wqb = (bf16*)p; p += DD * 2;
  bf16* wkb = (bf16*)p; p += DD * 2;
  bf16* wvb = (bf16*)p; p += DD * 2;
  bf16* wob = (bf16*)p; p += DD * 2;
  bf16* vtb  = kbf;   // kbf dead after gemm_qkv
  bf16* ctxb = qbf;   // qbf dead after gemm_qkv

  // fold softmax scale (1/sqrt(64)=1/8) and log2(e) into Wq for exp2-domain softmax
  const float wq_scale = 0.125f * 1.4426950408889634f;

  cvt_qkv<<<dim3(1024, 1, 3), 256, 0, stream>>>(q, k, v, qbf, kbf, vbf, (int)(BSD / 4));
  cvt_w<<<dim3(256, 1, 4), 256, 0, stream>>>(Wq, Wk, Wv, Wo, wqb, wkb, wvb, wob,
                                             (int)(DD / 4), wq_scale);

  gemm_qkv<<<dim3(Dn / 128, (Bn * Sn) / 128, 3), 256, 0, stream>>>(
      qbf, wqb, qpb, kbf, wkb, kpb, vbf, wvb, vpb);

  transpose_bsd<<<dim3(Sn / 64, Dn / 64, Bn), 256, 0, stream>>>(vpb, vtb);

  flash_attn<<<dim3(512), 512, 0, stream>>>(qpb, kpb, vtb, ctxb);

  gemm_out_f32<<<dim3(Dn / 128, (Bn * Sn) / 128), 256, 0, stream>>>(ctxb, wob, (float*)d_out);

  (void)in_sizes; (void)n_in; (void)out_size; (void)ws_size;
}